// Round 11
// baseline (626.689 us; speedup 1.0000x reference)
//
#include <hip/hip_runtime.h>

#define NEG_SLOPE 0.2f

typedef float vfloat4 __attribute__((ext_vector_type(4)));

// ---------------- CSR build ----------------

__global__ void zero_ints(int* __restrict__ p, int n) {
    int i = blockIdx.x * 256 + threadIdx.x;
    if (i < n) p[i] = 0;
}

__global__ void hist_kernel(const int* __restrict__ dst, int* __restrict__ deg, int E) {
    int i = blockIdx.x * 256 + threadIdx.x;
    if (i < E) atomicAdd(&deg[dst[i]], 1);
}

#define SCAN_CH 2048

__global__ __launch_bounds__(256) void scan_blocksum(const int* __restrict__ deg,
                                                     int* __restrict__ bsum, int N) {
    int blk = blockIdx.x, t = threadIdx.x;
    int base = blk * SCAN_CH;
    int s = 0;
#pragma unroll
    for (int i = 0; i < SCAN_CH / 256; ++i) {
        int idx = base + t + i * 256;
        if (idx < N) s += deg[idx];
    }
#pragma unroll
    for (int off = 1; off < 64; off <<= 1) s += __shfl_xor(s, off);
    __shared__ int wt[4];
    if ((t & 63) == 0) wt[t >> 6] = s;
    __syncthreads();
    if (t == 0) bsum[blk] = wt[0] + wt[1] + wt[2] + wt[3];
}

__global__ void scan_bsum(const int* __restrict__ bsum, int* __restrict__ boff, int nb) {
    int t = threadIdx.x;
    int orig = (t < nb) ? bsum[t] : 0;
    int v = orig;
#pragma unroll
    for (int off = 1; off < 64; off <<= 1) {
        int u = __shfl_up(v, off);
        if (t >= off) v += u;
    }
    if (t < nb) boff[t] = v - orig;
}

__global__ __launch_bounds__(256) void scan_write(const int* __restrict__ deg,
                                                  const int* __restrict__ boff,
                                                  int* __restrict__ rowptr, int N) {
    int blk = blockIdx.x, t = threadIdx.x;
    int base = blk * SCAN_CH + t * 8;
    int v[8];
    int s = 0;
#pragma unroll
    for (int r = 0; r < 8; ++r) {
        int idx = base + r;
        v[r] = (idx < N) ? deg[idx] : 0;
        s += v[r];
    }
    int lane = t & 63, wid = t >> 6;
    int p = s;
#pragma unroll
    for (int off = 1; off < 64; off <<= 1) {
        int u = __shfl_up(p, off);
        if (lane >= off) p += u;
    }
    __shared__ int wtot[4];
    if (lane == 63) wtot[wid] = p;
    __syncthreads();
    int run = boff[blk];
    for (int w = 0; w < wid; ++w) run += wtot[w];
    run += p - s;
#pragma unroll
    for (int r = 0; r < 8; ++r) {
        int idx = base + r;
        if (idx < N) {
            rowptr[idx] = run;
            run += v[r];
            if (idx == N - 1) rowptr[N] = run;
        }
    }
}

__global__ void fill_kernel(const int* __restrict__ src, const int* __restrict__ dst,
                            const int* __restrict__ rowptr, int* __restrict__ cursor,
                            int* __restrict__ csrc, int E) {
    int i = blockIdx.x * 256 + threadIdx.x;
    if (i < E) {
        int d = dst[i];
        int pos = atomicAdd(&cursor[d], 1);
        csrc[rowptr[d] + pos] = src[i];
    }
}

// -------- GEMM + fused el/er --------

template <int OUTF>
__global__ __launch_bounds__(256) void gemm_kernel(const float* __restrict__ X,
                                                   const float* __restrict__ W,
                                                   float* __restrict__ Y,
                                                   const float* __restrict__ as_,
                                                   const float* __restrict__ ad_,
                                                   float* __restrict__ el,
                                                   float* __restrict__ er, int N) {
    constexpr int K = 128;
    constexpr int MG = OUTF / 4;
    constexpr int NPB = (256 / MG) * 4;
    constexpr int H = OUTF / 32;
    __shared__ float ws[K * OUTF];
    __shared__ float xs[NPB * K];
    int t = threadIdx.x;
    int nbase = blockIdx.x * NPB;

    {
        const float4* Wg = (const float4*)W;
        float4* wl = (float4*)ws;
        constexpr int WIT = K * OUTF / 4 / 256;
#pragma unroll
        for (int i = 0; i < WIT; ++i) wl[t + i * 256] = Wg[t + i * 256];
    }
    {
        const float4* Xg = (const float4*)X;
        float4* xl = (float4*)xs;
        constexpr int XIT = NPB * K / 4 / 256;
#pragma unroll
        for (int i = 0; i < XIT; ++i) {
            int idx = t + i * 256;
            int n = idx >> 5, kq = idx & 31;
            int gn = nbase + n;
            gn = min(gn, N - 1);
            xl[idx] = Xg[(size_t)gn * 32 + kq];
        }
    }
    __syncthreads();

    int mg = t % MG, ngq = t / MG;
    int n0 = ngq * 4;
    float acc[4][4];
#pragma unroll
    for (int i = 0; i < 4; ++i)
#pragma unroll
        for (int j = 0; j < 4; ++j) acc[i][j] = 0.f;

    const float4* xsv = (const float4*)xs;
    const float4* wsv = (const float4*)ws;
    for (int k = 0; k < K; k += 4) {
        float4 xv[4], wv[4];
#pragma unroll
        for (int i = 0; i < 4; ++i) xv[i] = xsv[(n0 + i) * 32 + (k >> 2)];
#pragma unroll
        for (int kk = 0; kk < 4; ++kk) wv[kk] = wsv[(k + kk) * MG + mg];
#pragma unroll
        for (int i = 0; i < 4; ++i) {
#pragma unroll
            for (int kk = 0; kk < 4; ++kk) {
                float xf = ((const float*)&xv[i])[kk];
                acc[i][0] = fmaf(xf, wv[kk].x, acc[i][0]);
                acc[i][1] = fmaf(xf, wv[kk].y, acc[i][1]);
                acc[i][2] = fmaf(xf, wv[kk].z, acc[i][2]);
                acc[i][3] = fmaf(xf, wv[kk].w, acc[i][3]);
            }
        }
    }

    int h = mg >> 3;
    if (OUTF == 32) h = 0;
    float4 as4 = ((const float4*)as_)[mg];
    float4 ad4 = ((const float4*)ad_)[mg];

    float4* Yg = (float4*)Y;
#pragma unroll
    for (int i = 0; i < 4; ++i) {
        int gn = nbase + n0 + i;
        float pel = acc[i][0] * as4.x + acc[i][1] * as4.y + acc[i][2] * as4.z +
                    acc[i][3] * as4.w;
        float per = acc[i][0] * ad4.x + acc[i][1] * ad4.y + acc[i][2] * ad4.z +
                    acc[i][3] * ad4.w;
#pragma unroll
        for (int off = 1; off < 8; off <<= 1) {
            pel += __shfl_xor(pel, off);
            per += __shfl_xor(per, off);
        }
        if (gn < N) {
            float4 r;
            r.x = acc[i][0]; r.y = acc[i][1]; r.z = acc[i][2]; r.w = acc[i][3];
            Yg[(size_t)gn * MG + mg] = r;
            if ((mg & 7) == 0) {
                el[gn * H + h] = pel;
                er[gn * H + h] = per;
            }
        }
    }
}

// -------- edge weights: w[h][e] = exp(lrelu(el[src,h]+er[dst,h])), invd[n,h]=1/denom --------

template <int H>
__global__ __launch_bounds__(256) void weight_kernel(const float* __restrict__ el,
                                                     const float* __restrict__ er,
                                                     const int* __restrict__ rowptr,
                                                     const int* __restrict__ csrc,
                                                     float* __restrict__ wbuf,
                                                     float* __restrict__ invd,
                                                     int N, int E) {
    constexpr int NPW = 8;
    int lane = threadIdx.x & 63, wid = threadIdx.x >> 6;
    int nbase = blockIdx.x * (4 * NPW) + wid * NPW;
    int qe = (H == 4) ? (lane >> 2) : lane;
    int qh = (H == 4) ? (lane & 3) : 0;
    const int STEP = (H == 4) ? 16 : 64;

    for (int i = 0; i < NPW; ++i) {
        int node = nbase + i;
        if (node >= N) return;
        int row0 = __builtin_amdgcn_readfirstlane(rowptr[node]);
        int row1 = __builtin_amdgcn_readfirstlane(rowptr[node + 1]);
        float ern = er[node * H + qh];
        float dacc = 0.f;
        for (int base = row0; base < row1; base += STEP) {
            int e = base + qe;
            if (e < row1) {
                int s = __builtin_nontemporal_load(csrc + e);
                float tt = el[s * H + qh] + ern;
                tt = tt > 0.f ? tt : NEG_SLOPE * tt;
                float w = __expf(tt);
                dacc += w;
                __builtin_nontemporal_store(w, wbuf + (size_t)qh * E + e);
            }
        }
        if (H == 4) {
#pragma unroll
            for (int off = 4; off < 64; off <<= 1) dacc += __shfl_xor(dacc, off);
            if (qe == 0) invd[node * 4 + qh] = (row1 > row0) ? 1.f / dacc : 0.f;
        } else {
#pragma unroll
            for (int off = 1; off < 64; off <<= 1) dacc += __shfl_xor(dacc, off);
            if (lane == 0) invd[node] = (row1 > row0) ? 1.f / dacc : 0.f;
        }
    }
}

// -------- sliced aggregation: slice = blockIdx % NSLICE covers 16 feat cols --------
// Per-XCD feat working set = N*64B = 3.2 MB -> L2-resident (round-robin block->XCD).

template <int FEATDIM, int NSLICE, bool DOELU>
__global__ __launch_bounds__(256) void sagg_kernel(const float* __restrict__ feat,
                                                   const float* __restrict__ wbuf,
                                                   const float* __restrict__ invd,
                                                   const int* __restrict__ rowptr,
                                                   const int* __restrict__ csrc,
                                                   const float* __restrict__ bias,
                                                   float* __restrict__ out, int N, int E) {
    constexpr int NPW = 8;
    constexpr int H = FEATDIM / 32;
    int slice = blockIdx.x % NSLICE;
    int chunk = blockIdx.x / NSLICE;
    int lane = threadIdx.x & 63, wid = threadIdx.x >> 6;
    int qe = lane >> 2, cq = lane & 3;
    int hs = slice >> 1;              // head of this 16-col slice (0 when NSLICE=2)
    int col0 = slice * 16;
    const float* wh = wbuf + (size_t)hs * E;
    int nbase = chunk * (4 * NPW) + wid * NPW;

    float4 bv = *(const float4*)(bias + col0 + cq * 4);

    for (int i = 0; i < NPW; ++i) {
        int node = nbase + i;
        if (node >= N) return;
        int row0 = __builtin_amdgcn_readfirstlane(rowptr[node]);
        int row1 = __builtin_amdgcn_readfirstlane(rowptr[node + 1]);
        float a0 = 0.f, a1 = 0.f, a2 = 0.f, a3 = 0.f;
        for (int base = row0; base < row1; base += 16) {
            int e = base + qe;
            bool v = e < row1;
            int s = v ? __builtin_nontemporal_load(csrc + e) : 0;
            float w = v ? __builtin_nontemporal_load(wh + e) : 0.f;
            const float4 f = *(const float4*)(feat + (size_t)s * FEATDIM + col0 + cq * 4);
            a0 = fmaf(w, f.x, a0);
            a1 = fmaf(w, f.y, a1);
            a2 = fmaf(w, f.z, a2);
            a3 = fmaf(w, f.w, a3);
        }
#pragma unroll
        for (int off = 4; off < 64; off <<= 1) {
            a0 += __shfl_xor(a0, off);
            a1 += __shfl_xor(a1, off);
            a2 += __shfl_xor(a2, off);
            a3 += __shfl_xor(a3, off);
        }
        if (qe == 0) {
            float inv = invd[node * H + hs];
            float o0 = a0 * inv + bv.x;
            float o1 = a1 * inv + bv.y;
            float o2 = a2 * inv + bv.z;
            float o3 = a3 * inv + bv.w;
            if (DOELU) {
                o0 = o0 > 0.f ? o0 : __expf(o0) - 1.f;
                o1 = o1 > 0.f ? o1 : __expf(o1) - 1.f;
                o2 = o2 > 0.f ? o2 : __expf(o2) - 1.f;
                o3 = o3 > 0.f ? o3 : __expf(o3) - 1.f;
            }
            vfloat4 q;
            q.x = o0; q.y = o1; q.z = o2; q.w = o3;
            __builtin_nontemporal_store(
                q, (vfloat4*)(out + (size_t)node * FEATDIM + col0 + cq * 4));
        }
    }
}

// ---------------- host ----------------

extern "C" void kernel_launch(void* const* d_in, const int* in_sizes, int n_in,
                              void* d_out, int out_size, void* d_ws, size_t ws_size,
                              hipStream_t stream) {
    const float* features = (const float*)d_in[0];
    const int* esrc = (const int*)d_in[1];
    const int* edst = (const int*)d_in[2];
    const float* W1 = (const float*)d_in[3];
    const float* a1s = (const float*)d_in[4];
    const float* a1d = (const float*)d_in[5];
    const float* b1 = (const float*)d_in[6];
    const float* W2 = (const float*)d_in[7];
    const float* a2s = (const float*)d_in[8];
    const float* a2d = (const float*)d_in[9];
    const float* b2 = (const float*)d_in[10];
    const float* W3 = (const float*)d_in[11];
    const float* a3s = (const float*)d_in[12];
    const float* a3d = (const float*)d_in[13];
    const float* b3 = (const float*)d_in[14];

    int N = in_sizes[0] / 128;
    int E = in_sizes[1];
    int nb = (N + SCAN_CH - 1) / SCAN_CH;

    char* base = (char*)d_ws;
    size_t off = 0;
    auto nxt = [&](size_t bytes) {
        void* p = base + off;
        off += (bytes + 255) & ~(size_t)255;
        return p;
    };
    float* A = (float*)nxt((size_t)N * 128 * 4);   // feat
    float* B = (float*)nxt((size_t)N * 128 * 4);   // layer activations
    float* el = (float*)nxt((size_t)N * 4 * 4);
    float* er = (float*)nxt((size_t)N * 4 * 4);
    int* deg = (int*)nxt((size_t)N * 2 * 4);       // deg + cursor contiguous
    int* cursor = deg + N;
    int* rowptr = (int*)nxt((size_t)(N + 1) * 4);
    int* csrc = (int*)nxt((size_t)E * 4);
    int* bsum = (int*)nxt((size_t)(nb + 1) * 4);
    int* boff = (int*)nxt((size_t)(nb + 1) * 4);
    float* wbuf = (float*)nxt((size_t)E * 4 * 4);  // [4][E] edge weights
    float* invd = (float*)nxt((size_t)N * 4 * 4);  // [N][H] 1/denom

    int nwb = (N + 31) / 32;  // node-wave blocks (32 nodes/block)

    // CSR build (same graph for all 3 layers)
    zero_ints<<<(2 * N + 255) / 256, 256, 0, stream>>>(deg, 2 * N);
    hist_kernel<<<(E + 255) / 256, 256, 0, stream>>>(edst, deg, E);
    scan_blocksum<<<nb, 256, 0, stream>>>(deg, bsum, N);
    scan_bsum<<<1, 64, 0, stream>>>(bsum, boff, nb);
    scan_write<<<nb, 256, 0, stream>>>(deg, boff, rowptr, N);
    fill_kernel<<<(E + 255) / 256, 256, 0, stream>>>(esrc, edst, rowptr, cursor, csrc, E);

    // layer 1: 128 -> 4x32, ELU
    gemm_kernel<128><<<(N + 31) / 32, 256, 0, stream>>>(features, W1, A, a1s, a1d, el, er, N);
    weight_kernel<4><<<nwb, 256, 0, stream>>>(el, er, rowptr, csrc, wbuf, invd, N, E);
    sagg_kernel<128, 8, true><<<nwb * 8, 256, 0, stream>>>(A, wbuf, invd, rowptr, csrc,
                                                           b1, B, N, E);

    // layer 2: 128 -> 4x32, ELU
    gemm_kernel<128><<<(N + 31) / 32, 256, 0, stream>>>(B, W2, A, a2s, a2d, el, er, N);
    weight_kernel<4><<<nwb, 256, 0, stream>>>(el, er, rowptr, csrc, wbuf, invd, N, E);
    sagg_kernel<128, 8, true><<<nwb * 8, 256, 0, stream>>>(A, wbuf, invd, rowptr, csrc,
                                                           b2, B, N, E);

    // layer 3: 128 -> 1x32, no ELU, mean over 1 head = identity
    gemm_kernel<32><<<(N + 127) / 128, 256, 0, stream>>>(B, W3, A, a3s, a3d, el, er, N);
    weight_kernel<1><<<nwb, 256, 0, stream>>>(el, er, rowptr, csrc, wbuf, invd, N, E);
    sagg_kernel<32, 2, false><<<nwb * 2, 256, 0, stream>>>(A, wbuf, invd, rowptr, csrc,
                                                           b3, (float*)d_out, N, E);
}

// Round 12
// 274.633 us; speedup vs baseline: 2.2819x; 2.2819x over previous
//
#include <hip/hip_runtime.h>

#define NEG_SLOPE 0.2f

typedef unsigned int uint;
typedef unsigned short ushort;

__device__ __forceinline__ float bperm_f(int idx, float v) {
    return __int_as_float(__builtin_amdgcn_ds_bpermute(idx, __float_as_int(v)));
}

__device__ __forceinline__ uint pack_bf16x2(float a, float b) {
    uint ba = __float_as_uint(a);
    uint bb = __float_as_uint(b);
    uint ra = (ba + 0x7FFFu + ((ba >> 16) & 1u)) >> 16;
    uint rb = (bb + 0x7FFFu + ((bb >> 16) & 1u)) >> 16;
    return ra | (rb << 16);
}

__device__ __forceinline__ void unpack_bf16x2(uint u, float& lo, float& hi) {
    lo = __uint_as_float(u << 16);
    hi = __uint_as_float(u & 0xFFFF0000u);
}

// ---------------- CSR build ----------------

__global__ void zero_ints(int* __restrict__ p, int n) {
    int i = blockIdx.x * 256 + threadIdx.x;
    if (i < n) p[i] = 0;
}

__global__ void hist_kernel(const int* __restrict__ dst, int* __restrict__ deg, int E) {
    int i = blockIdx.x * 256 + threadIdx.x;
    if (i < E) atomicAdd(&deg[dst[i]], 1);
}

#define SCAN_CH 2048

__global__ __launch_bounds__(256) void scan_blocksum(const int* __restrict__ deg,
                                                     int* __restrict__ bsum, int N) {
    int blk = blockIdx.x, t = threadIdx.x;
    int base = blk * SCAN_CH;
    int s = 0;
#pragma unroll
    for (int i = 0; i < SCAN_CH / 256; ++i) {
        int idx = base + t + i * 256;
        if (idx < N) s += deg[idx];
    }
#pragma unroll
    for (int off = 1; off < 64; off <<= 1) s += __shfl_xor(s, off);
    __shared__ int wt[4];
    if ((t & 63) == 0) wt[t >> 6] = s;
    __syncthreads();
    if (t == 0) bsum[blk] = wt[0] + wt[1] + wt[2] + wt[3];
}

__global__ void scan_bsum(const int* __restrict__ bsum, int* __restrict__ boff, int nb) {
    int t = threadIdx.x;
    int orig = (t < nb) ? bsum[t] : 0;
    int v = orig;
#pragma unroll
    for (int off = 1; off < 64; off <<= 1) {
        int u = __shfl_up(v, off);
        if (t >= off) v += u;
    }
    if (t < nb) boff[t] = v - orig;
}

__global__ __launch_bounds__(256) void scan_write(const int* __restrict__ deg,
                                                  const int* __restrict__ boff,
                                                  int* __restrict__ rowptr, int N) {
    int blk = blockIdx.x, t = threadIdx.x;
    int base = blk * SCAN_CH + t * 8;
    int v[8];
    int s = 0;
#pragma unroll
    for (int r = 0; r < 8; ++r) {
        int idx = base + r;
        v[r] = (idx < N) ? deg[idx] : 0;
        s += v[r];
    }
    int lane = t & 63, wid = t >> 6;
    int p = s;
#pragma unroll
    for (int off = 1; off < 64; off <<= 1) {
        int u = __shfl_up(p, off);
        if (lane >= off) p += u;
    }
    __shared__ int wtot[4];
    if (lane == 63) wtot[wid] = p;
    __syncthreads();
    int run = boff[blk];
    for (int w = 0; w < wid; ++w) run += wtot[w];
    run += p - s;
#pragma unroll
    for (int r = 0; r < 8; ++r) {
        int idx = base + r;
        if (idx < N) {
            rowptr[idx] = run;
            run += v[r];
            if (idx == N - 1) rowptr[N] = run;
        }
    }
}

__global__ void fill_kernel(const int* __restrict__ src, const int* __restrict__ dst,
                            const int* __restrict__ rowptr, int* __restrict__ cursor,
                            int* __restrict__ csrc, int E) {
    int i = blockIdx.x * 256 + threadIdx.x;
    if (i < E) {
        int d = dst[i];
        int pos = atomicAdd(&cursor[d], 1);
        csrc[rowptr[d] + pos] = src[i];
    }
}

// -------- GEMM + fused el/er. BF16OUT: write bf16 rows (no fp32 Y) --------

template <int OUTF, bool BF16OUT>
__global__ __launch_bounds__(256) void gemm_kernel(const float* __restrict__ X,
                                                   const float* __restrict__ W,
                                                   float* __restrict__ Y,
                                                   ushort* __restrict__ Yb,
                                                   const float* __restrict__ as_,
                                                   const float* __restrict__ ad_,
                                                   float* __restrict__ el,
                                                   float* __restrict__ er, int N) {
    constexpr int K = 128;
    constexpr int MG = OUTF / 4;
    constexpr int NPB = (256 / MG) * 4;
    constexpr int H = OUTF / 32;
    __shared__ float ws[K * OUTF];
    __shared__ float xs[NPB * K];
    int t = threadIdx.x;
    int nbase = blockIdx.x * NPB;

    {
        const float4* Wg = (const float4*)W;
        float4* wl = (float4*)ws;
        constexpr int WIT = K * OUTF / 4 / 256;
#pragma unroll
        for (int i = 0; i < WIT; ++i) wl[t + i * 256] = Wg[t + i * 256];
    }
    {
        const float4* Xg = (const float4*)X;
        float4* xl = (float4*)xs;
        constexpr int XIT = NPB * K / 4 / 256;
#pragma unroll
        for (int i = 0; i < XIT; ++i) {
            int idx = t + i * 256;
            int n = idx >> 5, kq = idx & 31;
            int gn = nbase + n;
            gn = min(gn, N - 1);
            xl[idx] = Xg[(size_t)gn * 32 + kq];
        }
    }
    __syncthreads();

    int mg = t % MG, ngq = t / MG;
    int n0 = ngq * 4;
    float acc[4][4];
#pragma unroll
    for (int i = 0; i < 4; ++i)
#pragma unroll
        for (int j = 0; j < 4; ++j) acc[i][j] = 0.f;

    const float4* xsv = (const float4*)xs;
    const float4* wsv = (const float4*)ws;
    for (int k = 0; k < K; k += 4) {
        float4 xv[4], wv[4];
#pragma unroll
        for (int i = 0; i < 4; ++i) xv[i] = xsv[(n0 + i) * 32 + (k >> 2)];
#pragma unroll
        for (int kk = 0; kk < 4; ++kk) wv[kk] = wsv[(k + kk) * MG + mg];
#pragma unroll
        for (int i = 0; i < 4; ++i) {
#pragma unroll
            for (int kk = 0; kk < 4; ++kk) {
                float xf = ((const float*)&xv[i])[kk];
                acc[i][0] = fmaf(xf, wv[kk].x, acc[i][0]);
                acc[i][1] = fmaf(xf, wv[kk].y, acc[i][1]);
                acc[i][2] = fmaf(xf, wv[kk].z, acc[i][2]);
                acc[i][3] = fmaf(xf, wv[kk].w, acc[i][3]);
            }
        }
    }

    int h = mg >> 3;
    if (OUTF == 32) h = 0;
    float4 as4 = ((const float4*)as_)[mg];
    float4 ad4 = ((const float4*)ad_)[mg];

#pragma unroll
    for (int i = 0; i < 4; ++i) {
        int gn = nbase + n0 + i;
        float pel = acc[i][0] * as4.x + acc[i][1] * as4.y + acc[i][2] * as4.z +
                    acc[i][3] * as4.w;
        float per = acc[i][0] * ad4.x + acc[i][1] * ad4.y + acc[i][2] * ad4.z +
                    acc[i][3] * ad4.w;
#pragma unroll
        for (int off = 1; off < 8; off <<= 1) {
            pel += __shfl_xor(pel, off);
            per += __shfl_xor(per, off);
        }
        if (gn < N) {
            if (BF16OUT) {
                uint2 pv;
                pv.x = pack_bf16x2(acc[i][0], acc[i][1]);
                pv.y = pack_bf16x2(acc[i][2], acc[i][3]);
                ((uint2*)Yb)[(size_t)gn * MG + mg] = pv;
            } else {
                float4 r;
                r.x = acc[i][0]; r.y = acc[i][1]; r.z = acc[i][2]; r.w = acc[i][3];
                ((float4*)Y)[(size_t)gn * MG + mg] = r;
            }
            if ((mg & 7) == 0) {
                el[gn * H + h] = pel;
                er[gn * H + h] = per;
            }
        }
    }
}

// ---------------- aggregation (H=4, bf16 feat): one wave per dst node ----------------
// Weight phase: 16-edge batches, lane m: edge m>>2, head m&3.
// Gather: straight-line 4 iterations; lane li of group g reads 16B (8 bf16).

template <bool DOELU>
__global__ __launch_bounds__(256) void agg4_kernel(const ushort* __restrict__ featb,
                                                   const float* __restrict__ el,
                                                   const float* __restrict__ er,
                                                   const int* __restrict__ rowptr,
                                                   const int* __restrict__ csrc,
                                                   const float* __restrict__ bias,
                                                   float* __restrict__ out, int N) {
    int lane = threadIdx.x & 63;
    int node = blockIdx.x * 4 + (threadIdx.x >> 6);
    if (node >= N) return;
    int row0 = __builtin_amdgcn_readfirstlane(rowptr[node]);
    int row1 = __builtin_amdgcn_readfirstlane(rowptr[node + 1]);

    int qe = lane >> 2;
    int qh = lane & 3;
    float ern = er[node * 4 + qh];

    int g = lane >> 4;
    int li = lane & 15;
    int h = li >> 2;
    int ib = (g << 4) + (h << 2);  // bpermute byte base: lane (g*4+h), iter 0

    float dacc = 0.f;
    float acc[8];
#pragma unroll
    for (int r = 0; r < 8; ++r) acc[r] = 0.f;

    for (int base = row0; base < row1; base += 16) {
        int e = base + qe;
        int s = 0;
        float w = 0.f;
        if (e < row1) {
            s = csrc[e];
            float tt = el[s * 4 + qh] + ern;
            tt = tt > 0.f ? tt : NEG_SLOPE * tt;
            w = __expf(tt);
            dacc += w;
        }
        int sj0 = __builtin_amdgcn_ds_bpermute(ib, s);
        float w0 = bperm_f(ib, w);
        int sj1 = __builtin_amdgcn_ds_bpermute(ib + 64, s);
        float w1 = bperm_f(ib + 64, w);
        int sj2 = __builtin_amdgcn_ds_bpermute(ib + 128, s);
        float w2 = bperm_f(ib + 128, w);
        int sj3 = __builtin_amdgcn_ds_bpermute(ib + 192, s);
        float w3 = bperm_f(ib + 192, w);
        uint4 U0 = *(const uint4*)(featb + (size_t)sj0 * 128 + li * 8);
        uint4 U1 = *(const uint4*)(featb + (size_t)sj1 * 128 + li * 8);
        uint4 U2 = *(const uint4*)(featb + (size_t)sj2 * 128 + li * 8);
        uint4 U3 = *(const uint4*)(featb + (size_t)sj3 * 128 + li * 8);
        float f0, f1, f2, f3, f4, f5, f6, f7;
        unpack_bf16x2(U0.x, f0, f1); unpack_bf16x2(U0.y, f2, f3);
        unpack_bf16x2(U0.z, f4, f5); unpack_bf16x2(U0.w, f6, f7);
        acc[0] = fmaf(w0, f0, acc[0]); acc[1] = fmaf(w0, f1, acc[1]);
        acc[2] = fmaf(w0, f2, acc[2]); acc[3] = fmaf(w0, f3, acc[3]);
        acc[4] = fmaf(w0, f4, acc[4]); acc[5] = fmaf(w0, f5, acc[5]);
        acc[6] = fmaf(w0, f6, acc[6]); acc[7] = fmaf(w0, f7, acc[7]);
        unpack_bf16x2(U1.x, f0, f1); unpack_bf16x2(U1.y, f2, f3);
        unpack_bf16x2(U1.z, f4, f5); unpack_bf16x2(U1.w, f6, f7);
        acc[0] = fmaf(w1, f0, acc[0]); acc[1] = fmaf(w1, f1, acc[1]);
        acc[2] = fmaf(w1, f2, acc[2]); acc[3] = fmaf(w1, f3, acc[3]);
        acc[4] = fmaf(w1, f4, acc[4]); acc[5] = fmaf(w1, f5, acc[5]);
        acc[6] = fmaf(w1, f6, acc[6]); acc[7] = fmaf(w1, f7, acc[7]);
        unpack_bf16x2(U2.x, f0, f1); unpack_bf16x2(U2.y, f2, f3);
        unpack_bf16x2(U2.z, f4, f5); unpack_bf16x2(U2.w, f6, f7);
        acc[0] = fmaf(w2, f0, acc[0]); acc[1] = fmaf(w2, f1, acc[1]);
        acc[2] = fmaf(w2, f2, acc[2]); acc[3] = fmaf(w2, f3, acc[3]);
        acc[4] = fmaf(w2, f4, acc[4]); acc[5] = fmaf(w2, f5, acc[5]);
        acc[6] = fmaf(w2, f6, acc[6]); acc[7] = fmaf(w2, f7, acc[7]);
        unpack_bf16x2(U3.x, f0, f1); unpack_bf16x2(U3.y, f2, f3);
        unpack_bf16x2(U3.z, f4, f5); unpack_bf16x2(U3.w, f6, f7);
        acc[0] = fmaf(w3, f0, acc[0]); acc[1] = fmaf(w3, f1, acc[1]);
        acc[2] = fmaf(w3, f2, acc[2]); acc[3] = fmaf(w3, f3, acc[3]);
        acc[4] = fmaf(w3, f4, acc[4]); acc[5] = fmaf(w3, f5, acc[5]);
        acc[6] = fmaf(w3, f6, acc[6]); acc[7] = fmaf(w3, f7, acc[7]);
    }

#pragma unroll
    for (int r = 0; r < 8; ++r) {
        acc[r] += __shfl_xor(acc[r], 16);
        acc[r] += __shfl_xor(acc[r], 32);
    }
#pragma unroll
    for (int off = 4; off < 64; off <<= 1) dacc += __shfl_xor(dacc, off);
    float d = bperm_f((li >> 2) << 2, dacc);

    if (lane < 16) {
        float inv = (row1 > row0) ? 1.f / d : 0.f;
        const float4* bv = (const float4*)bias + li * 2;
        float4 b0 = bv[0], b1 = bv[1];
        float o[8];
#pragma unroll
        for (int r = 0; r < 8; ++r) o[r] = acc[r] * inv;
        o[0] += b0.x; o[1] += b0.y; o[2] += b0.z; o[3] += b0.w;
        o[4] += b1.x; o[5] += b1.y; o[6] += b1.z; o[7] += b1.w;
        if (DOELU) {
#pragma unroll
            for (int r = 0; r < 8; ++r) o[r] = o[r] > 0.f ? o[r] : __expf(o[r]) - 1.f;
        }
        float4 q0, q1;
        q0.x = o[0]; q0.y = o[1]; q0.z = o[2]; q0.w = o[3];
        q1.x = o[4]; q1.y = o[5]; q1.z = o[6]; q1.w = o[7];
        float4* ov = (float4*)(out + (size_t)node * 128) + li * 2;
        ov[0] = q0;
        ov[1] = q1;
    }
}

// ---------------- aggregation (H=1, fp32 feat): one wave per dst node ----------------

__global__ __launch_bounds__(256) void agg1_kernel(const float* __restrict__ feat,
                                                   const float* __restrict__ el,
                                                   const float* __restrict__ er,
                                                   const int* __restrict__ rowptr,
                                                   const int* __restrict__ csrc,
                                                   const float* __restrict__ bias,
                                                   float* __restrict__ out, int N) {
    int lane = threadIdx.x & 63;
    int node = blockIdx.x * 4 + (threadIdx.x >> 6);
    if (node >= N) return;
    int row0 = __builtin_amdgcn_readfirstlane(rowptr[node]);
    int row1 = __builtin_amdgcn_readfirstlane(rowptr[node + 1]);

    float ern = er[node];
    int g = lane >> 3;
    int li = lane & 7;

    float dacc = 0.f;
    float acc[4];
#pragma unroll
    for (int r = 0; r < 4; ++r) acc[r] = 0.f;

    for (int base = row0; base < row1; base += 64) {
        int e = base + lane;
        int s = 0;
        float w0 = 0.f;
        if (e < row1) {
            s = csrc[e];
            float t0 = el[s] + ern;
            t0 = t0 > 0.f ? t0 : NEG_SLOPE * t0;
            w0 = __expf(t0);
            dacc += w0;
        }
        int cnt = min(row1 - base, 64);
        int iters = (cnt + 7) >> 3;
        int it = 0;
        for (; it + 1 < iters; it += 2) {
            int idxA = ((it << 3) + g) << 2;
            int idxB = (((it + 1) << 3) + g) << 2;
            int sjA = __builtin_amdgcn_ds_bpermute(idxA, s);
            float wA = bperm_f(idxA, w0);
            int sjB = __builtin_amdgcn_ds_bpermute(idxB, s);
            float wB = bperm_f(idxB, w0);
            const float4* fpA = (const float4*)(feat + (size_t)sjA * 32) + li;
            const float4* fpB = (const float4*)(feat + (size_t)sjB * 32) + li;
            float4 a0 = fpA[0], b0 = fpB[0];
            acc[0] = fmaf(wA, a0.x, acc[0]); acc[1] = fmaf(wA, a0.y, acc[1]);
            acc[2] = fmaf(wA, a0.z, acc[2]); acc[3] = fmaf(wA, a0.w, acc[3]);
            acc[0] = fmaf(wB, b0.x, acc[0]); acc[1] = fmaf(wB, b0.y, acc[1]);
            acc[2] = fmaf(wB, b0.z, acc[2]); acc[3] = fmaf(wB, b0.w, acc[3]);
        }
        if (it < iters) {
            int idx = ((it << 3) + g) << 2;
            int sj = __builtin_amdgcn_ds_bpermute(idx, s);
            float wsel = bperm_f(idx, w0);
            const float4* fp = (const float4*)(feat + (size_t)sj * 32) + li;
            float4 v0 = fp[0];
            acc[0] = fmaf(wsel, v0.x, acc[0]); acc[1] = fmaf(wsel, v0.y, acc[1]);
            acc[2] = fmaf(wsel, v0.z, acc[2]); acc[3] = fmaf(wsel, v0.w, acc[3]);
        }
    }

#pragma unroll
    for (int r = 0; r < 4; ++r) {
        acc[r] += __shfl_xor(acc[r], 8);
        acc[r] += __shfl_xor(acc[r], 16);
        acc[r] += __shfl_xor(acc[r], 32);
    }
#pragma unroll
    for (int off = 1; off < 64; off <<= 1) dacc += __shfl_xor(dacc, off);

    if (lane < 8) {
        float inv = (row1 > row0) ? 1.f / dacc : 0.f;
        float4 b0 = ((const float4*)bias)[lane];
        float4 q;
        q.x = acc[0] * inv + b0.x;
        q.y = acc[1] * inv + b0.y;
        q.z = acc[2] * inv + b0.z;
        q.w = acc[3] * inv + b0.w;
        ((float4*)(out + (size_t)node * 32))[lane] = q;
    }
}

// ---------------- host ----------------

extern "C" void kernel_launch(void* const* d_in, const int* in_sizes, int n_in,
                              void* d_out, int out_size, void* d_ws, size_t ws_size,
                              hipStream_t stream) {
    const float* features = (const float*)d_in[0];
    const int* esrc = (const int*)d_in[1];
    const int* edst = (const int*)d_in[2];
    const float* W1 = (const float*)d_in[3];
    const float* a1s = (const float*)d_in[4];
    const float* a1d = (const float*)d_in[5];
    const float* b1 = (const float*)d_in[6];
    const float* W2 = (const float*)d_in[7];
    const float* a2s = (const float*)d_in[8];
    const float* a2d = (const float*)d_in[9];
    const float* b2 = (const float*)d_in[10];
    const float* W3 = (const float*)d_in[11];
    const float* a3s = (const float*)d_in[12];
    const float* a3d = (const float*)d_in[13];
    const float* b3 = (const float*)d_in[14];

    int N = in_sizes[0] / 128;
    int E = in_sizes[1];
    int nb = (N + SCAN_CH - 1) / SCAN_CH;

    char* base = (char*)d_ws;
    size_t off = 0;
    auto nxt = [&](size_t bytes) {
        void* p = base + off;
        off += (bytes + 255) & ~(size_t)255;
        return p;
    };
    ushort* Yb = (ushort*)nxt((size_t)N * 128 * 2);  // bf16 feat (layers 1-2)
    float* B = (float*)nxt((size_t)N * 128 * 4);     // agg4 fp32 output
    float* A2 = (float*)nxt((size_t)N * 32 * 4);     // gemm32 fp32 output
    float* el = (float*)nxt((size_t)N * 4 * 4);
    float* er = (float*)nxt((size_t)N * 4 * 4);
    int* deg = (int*)nxt((size_t)N * 2 * 4);         // deg + cursor contiguous
    int* cursor = deg + N;
    int* rowptr = (int*)nxt((size_t)(N + 1) * 4);
    int* csrc = (int*)nxt((size_t)E * 4);
    int* bsum = (int*)nxt((size_t)(nb + 1) * 4);
    int* boff = (int*)nxt((size_t)(nb + 1) * 4);

    // CSR build (same graph for all 3 layers)
    zero_ints<<<(2 * N + 255) / 256, 256, 0, stream>>>(deg, 2 * N);
    hist_kernel<<<(E + 255) / 256, 256, 0, stream>>>(edst, deg, E);
    scan_blocksum<<<nb, 256, 0, stream>>>(deg, bsum, N);
    scan_bsum<<<1, 64, 0, stream>>>(bsum, boff, nb);
    scan_write<<<nb, 256, 0, stream>>>(deg, boff, rowptr, N);
    fill_kernel<<<(E + 255) / 256, 256, 0, stream>>>(esrc, edst, rowptr, cursor, csrc, E);

    // layer 1: 128 -> 4x32, ELU
    gemm_kernel<128, true><<<(N + 31) / 32, 256, 0, stream>>>(features, W1, nullptr, Yb,
                                                              a1s, a1d, el, er, N);
    agg4_kernel<true><<<(N + 3) / 4, 256, 0, stream>>>(Yb, el, er, rowptr, csrc, b1, B, N);

    // layer 2: 128 -> 4x32, ELU
    gemm_kernel<128, true><<<(N + 31) / 32, 256, 0, stream>>>(B, W2, nullptr, Yb,
                                                              a2s, a2d, el, er, N);
    agg4_kernel<true><<<(N + 3) / 4, 256, 0, stream>>>(Yb, el, er, rowptr, csrc, b2, B, N);

    // layer 3: 128 -> 1x32, no ELU, mean over 1 head = identity (fp32 path)
    gemm_kernel<32, false><<<(N + 127) / 128, 256, 0, stream>>>(B, W3, A2, nullptr,
                                                                a3s, a3d, el, er, N);
    agg1_kernel<<<(N + 3) / 4, 256, 0, stream>>>(A2, el, er, rowptr, csrc, b3,
                                                 (float*)d_out, N);
}

// Round 13
// 253.040 us; speedup vs baseline: 2.4766x; 1.0853x over previous
//
#include <hip/hip_runtime.h>

#define NEG_SLOPE 0.2f

typedef unsigned int uint;
typedef unsigned short ushort;

__device__ __forceinline__ float bperm_f(int idx, float v) {
    return __int_as_float(__builtin_amdgcn_ds_bpermute(idx, __float_as_int(v)));
}

__device__ __forceinline__ uint pack_bf16x2(float a, float b) {
    uint ba = __float_as_uint(a);
    uint bb = __float_as_uint(b);
    uint ra = (ba + 0x7FFFu + ((ba >> 16) & 1u)) >> 16;
    uint rb = (bb + 0x7FFFu + ((bb >> 16) & 1u)) >> 16;
    return ra | (rb << 16);
}

__device__ __forceinline__ void unpack_bf16x2(uint u, float& lo, float& hi) {
    lo = __uint_as_float(u << 16);
    hi = __uint_as_float(u & 0xFFFF0000u);
}

// ---------------- CSR build ----------------

__global__ void zero_ints(int* __restrict__ p, int n) {
    int i = blockIdx.x * 256 + threadIdx.x;
    if (i < n) p[i] = 0;
}

// histogram + per-edge rank (atomic return value = rank within dst row)
__global__ void hist_kernel(const int* __restrict__ dst, int* __restrict__ deg,
                            int* __restrict__ rank, int E) {
    int i = blockIdx.x * 256 + threadIdx.x;
    if (i < E) rank[i] = atomicAdd(&deg[dst[i]], 1);
}

#define SCAN_CH 2048

__global__ __launch_bounds__(256) void scan_blocksum(const int* __restrict__ deg,
                                                     int* __restrict__ bsum, int N) {
    int blk = blockIdx.x, t = threadIdx.x;
    int base = blk * SCAN_CH;
    int s = 0;
#pragma unroll
    for (int i = 0; i < SCAN_CH / 256; ++i) {
        int idx = base + t + i * 256;
        if (idx < N) s += deg[idx];
    }
#pragma unroll
    for (int off = 1; off < 64; off <<= 1) s += __shfl_xor(s, off);
    __shared__ int wt[4];
    if ((t & 63) == 0) wt[t >> 6] = s;
    __syncthreads();
    if (t == 0) bsum[blk] = wt[0] + wt[1] + wt[2] + wt[3];
}

__global__ void scan_bsum(const int* __restrict__ bsum, int* __restrict__ boff, int nb) {
    int t = threadIdx.x;
    int orig = (t < nb) ? bsum[t] : 0;
    int v = orig;
#pragma unroll
    for (int off = 1; off < 64; off <<= 1) {
        int u = __shfl_up(v, off);
        if (t >= off) v += u;
    }
    if (t < nb) boff[t] = v - orig;
}

__global__ __launch_bounds__(256) void scan_write(const int* __restrict__ deg,
                                                  const int* __restrict__ boff,
                                                  int* __restrict__ rowptr, int N) {
    int blk = blockIdx.x, t = threadIdx.x;
    int base = blk * SCAN_CH + t * 8;
    int v[8];
    int s = 0;
#pragma unroll
    for (int r = 0; r < 8; ++r) {
        int idx = base + r;
        v[r] = (idx < N) ? deg[idx] : 0;
        s += v[r];
    }
    int lane = t & 63, wid = t >> 6;
    int p = s;
#pragma unroll
    for (int off = 1; off < 64; off <<= 1) {
        int u = __shfl_up(p, off);
        if (lane >= off) p += u;
    }
    __shared__ int wtot[4];
    if (lane == 63) wtot[wid] = p;
    __syncthreads();
    int run = boff[blk];
    for (int w = 0; w < wid; ++w) run += wtot[w];
    run += p - s;
#pragma unroll
    for (int r = 0; r < 8; ++r) {
        int idx = base + r;
        if (idx < N) {
            rowptr[idx] = run;
            run += v[r];
            if (idx == N - 1) rowptr[N] = run;
        }
    }
}

// pure scatter, no atomic dependency: position = rowptr[dst] + precomputed rank
__global__ void fill_kernel(const int* __restrict__ src, const int* __restrict__ dst,
                            const int* __restrict__ rowptr, const int* __restrict__ rank,
                            int* __restrict__ csrc, int E) {
    int i = blockIdx.x * 256 + threadIdx.x;
    if (i < E) {
        int d = dst[i];
        __builtin_nontemporal_store(src[i], csrc + rowptr[d] + rank[i]);
    }
}

// -------- GEMM + fused el/er. BF16OUT: write bf16 rows (no fp32 Y) --------

template <int OUTF, bool BF16OUT>
__global__ __launch_bounds__(256) void gemm_kernel(const float* __restrict__ X,
                                                   const float* __restrict__ W,
                                                   float* __restrict__ Y,
                                                   ushort* __restrict__ Yb,
                                                   const float* __restrict__ as_,
                                                   const float* __restrict__ ad_,
                                                   float* __restrict__ el,
                                                   float* __restrict__ er, int N) {
    constexpr int K = 128;
    constexpr int MG = OUTF / 4;
    constexpr int NPB = (256 / MG) * 4;
    constexpr int H = OUTF / 32;
    __shared__ float ws[K * OUTF];
    __shared__ float xs[NPB * K];
    int t = threadIdx.x;
    int nbase = blockIdx.x * NPB;

    {
        const float4* Wg = (const float4*)W;
        float4* wl = (float4*)ws;
        constexpr int WIT = K * OUTF / 4 / 256;
#pragma unroll
        for (int i = 0; i < WIT; ++i) wl[t + i * 256] = Wg[t + i * 256];
    }
    {
        const float4* Xg = (const float4*)X;
        float4* xl = (float4*)xs;
        constexpr int XIT = NPB * K / 4 / 256;
#pragma unroll
        for (int i = 0; i < XIT; ++i) {
            int idx = t + i * 256;
            int n = idx >> 5, kq = idx & 31;
            int gn = nbase + n;
            gn = min(gn, N - 1);
            xl[idx] = Xg[(size_t)gn * 32 + kq];
        }
    }
    __syncthreads();

    int mg = t % MG, ngq = t / MG;
    int n0 = ngq * 4;
    float acc[4][4];
#pragma unroll
    for (int i = 0; i < 4; ++i)
#pragma unroll
        for (int j = 0; j < 4; ++j) acc[i][j] = 0.f;

    const float4* xsv = (const float4*)xs;
    const float4* wsv = (const float4*)ws;
    for (int k = 0; k < K; k += 4) {
        float4 xv[4], wv[4];
#pragma unroll
        for (int i = 0; i < 4; ++i) xv[i] = xsv[(n0 + i) * 32 + (k >> 2)];
#pragma unroll
        for (int kk = 0; kk < 4; ++kk) wv[kk] = wsv[(k + kk) * MG + mg];
#pragma unroll
        for (int i = 0; i < 4; ++i) {
#pragma unroll
            for (int kk = 0; kk < 4; ++kk) {
                float xf = ((const float*)&xv[i])[kk];
                acc[i][0] = fmaf(xf, wv[kk].x, acc[i][0]);
                acc[i][1] = fmaf(xf, wv[kk].y, acc[i][1]);
                acc[i][2] = fmaf(xf, wv[kk].z, acc[i][2]);
                acc[i][3] = fmaf(xf, wv[kk].w, acc[i][3]);
            }
        }
    }

    int h = mg >> 3;
    if (OUTF == 32) h = 0;
    float4 as4 = ((const float4*)as_)[mg];
    float4 ad4 = ((const float4*)ad_)[mg];

#pragma unroll
    for (int i = 0; i < 4; ++i) {
        int gn = nbase + n0 + i;
        float pel = acc[i][0] * as4.x + acc[i][1] * as4.y + acc[i][2] * as4.z +
                    acc[i][3] * as4.w;
        float per = acc[i][0] * ad4.x + acc[i][1] * ad4.y + acc[i][2] * ad4.z +
                    acc[i][3] * ad4.w;
#pragma unroll
        for (int off = 1; off < 8; off <<= 1) {
            pel += __shfl_xor(pel, off);
            per += __shfl_xor(per, off);
        }
        if (gn < N) {
            if (BF16OUT) {
                uint2 pv;
                pv.x = pack_bf16x2(acc[i][0], acc[i][1]);
                pv.y = pack_bf16x2(acc[i][2], acc[i][3]);
                ((uint2*)Yb)[(size_t)gn * MG + mg] = pv;
            } else {
                float4 r;
                r.x = acc[i][0]; r.y = acc[i][1]; r.z = acc[i][2]; r.w = acc[i][3];
                ((float4*)Y)[(size_t)gn * MG + mg] = r;
            }
            if ((mg & 7) == 0) {
                el[gn * H + h] = pel;
                er[gn * H + h] = per;
            }
        }
    }
}

// ---------------- aggregation (H=4, bf16 feat): one wave per dst node ----------------

template <bool DOELU>
__global__ __launch_bounds__(256) void agg4_kernel(const ushort* __restrict__ featb,
                                                   const float* __restrict__ el,
                                                   const float* __restrict__ er,
                                                   const int* __restrict__ rowptr,
                                                   const int* __restrict__ csrc,
                                                   const float* __restrict__ bias,
                                                   float* __restrict__ out, int N) {
    int lane = threadIdx.x & 63;
    int node = blockIdx.x * 4 + (threadIdx.x >> 6);
    if (node >= N) return;
    int row0 = __builtin_amdgcn_readfirstlane(rowptr[node]);
    int row1 = __builtin_amdgcn_readfirstlane(rowptr[node + 1]);

    int qe = lane >> 2;
    int qh = lane & 3;
    float ern = er[node * 4 + qh];

    int g = lane >> 4;
    int li = lane & 15;
    int h = li >> 2;
    int ib = (g << 4) + (h << 2);  // bpermute byte base: lane (g*4+h), iter 0

    float dacc = 0.f;
    float acc[8];
#pragma unroll
    for (int r = 0; r < 8; ++r) acc[r] = 0.f;

    for (int base = row0; base < row1; base += 16) {
        int e = base + qe;
        int s = 0;
        float w = 0.f;
        if (e < row1) {
            s = csrc[e];
            float tt = el[s * 4 + qh] + ern;
            tt = tt > 0.f ? tt : NEG_SLOPE * tt;
            w = __expf(tt);
            dacc += w;
        }
        int sj0 = __builtin_amdgcn_ds_bpermute(ib, s);
        float w0 = bperm_f(ib, w);
        int sj1 = __builtin_amdgcn_ds_bpermute(ib + 64, s);
        float w1 = bperm_f(ib + 64, w);
        int sj2 = __builtin_amdgcn_ds_bpermute(ib + 128, s);
        float w2 = bperm_f(ib + 128, w);
        int sj3 = __builtin_amdgcn_ds_bpermute(ib + 192, s);
        float w3 = bperm_f(ib + 192, w);
        uint4 U0 = *(const uint4*)(featb + (size_t)sj0 * 128 + li * 8);
        uint4 U1 = *(const uint4*)(featb + (size_t)sj1 * 128 + li * 8);
        uint4 U2 = *(const uint4*)(featb + (size_t)sj2 * 128 + li * 8);
        uint4 U3 = *(const uint4*)(featb + (size_t)sj3 * 128 + li * 8);
        float f0, f1, f2, f3, f4, f5, f6, f7;
        unpack_bf16x2(U0.x, f0, f1); unpack_bf16x2(U0.y, f2, f3);
        unpack_bf16x2(U0.z, f4, f5); unpack_bf16x2(U0.w, f6, f7);
        acc[0] = fmaf(w0, f0, acc[0]); acc[1] = fmaf(w0, f1, acc[1]);
        acc[2] = fmaf(w0, f2, acc[2]); acc[3] = fmaf(w0, f3, acc[3]);
        acc[4] = fmaf(w0, f4, acc[4]); acc[5] = fmaf(w0, f5, acc[5]);
        acc[6] = fmaf(w0, f6, acc[6]); acc[7] = fmaf(w0, f7, acc[7]);
        unpack_bf16x2(U1.x, f0, f1); unpack_bf16x2(U1.y, f2, f3);
        unpack_bf16x2(U1.z, f4, f5); unpack_bf16x2(U1.w, f6, f7);
        acc[0] = fmaf(w1, f0, acc[0]); acc[1] = fmaf(w1, f1, acc[1]);
        acc[2] = fmaf(w1, f2, acc[2]); acc[3] = fmaf(w1, f3, acc[3]);
        acc[4] = fmaf(w1, f4, acc[4]); acc[5] = fmaf(w1, f5, acc[5]);
        acc[6] = fmaf(w1, f6, acc[6]); acc[7] = fmaf(w1, f7, acc[7]);
        unpack_bf16x2(U2.x, f0, f1); unpack_bf16x2(U2.y, f2, f3);
        unpack_bf16x2(U2.z, f4, f5); unpack_bf16x2(U2.w, f6, f7);
        acc[0] = fmaf(w2, f0, acc[0]); acc[1] = fmaf(w2, f1, acc[1]);
        acc[2] = fmaf(w2, f2, acc[2]); acc[3] = fmaf(w2, f3, acc[3]);
        acc[4] = fmaf(w2, f4, acc[4]); acc[5] = fmaf(w2, f5, acc[5]);
        acc[6] = fmaf(w2, f6, acc[6]); acc[7] = fmaf(w2, f7, acc[7]);
        unpack_bf16x2(U3.x, f0, f1); unpack_bf16x2(U3.y, f2, f3);
        unpack_bf16x2(U3.z, f4, f5); unpack_bf16x2(U3.w, f6, f7);
        acc[0] = fmaf(w3, f0, acc[0]); acc[1] = fmaf(w3, f1, acc[1]);
        acc[2] = fmaf(w3, f2, acc[2]); acc[3] = fmaf(w3, f3, acc[3]);
        acc[4] = fmaf(w3, f4, acc[4]); acc[5] = fmaf(w3, f5, acc[5]);
        acc[6] = fmaf(w3, f6, acc[6]); acc[7] = fmaf(w3, f7, acc[7]);
    }

#pragma unroll
    for (int r = 0; r < 8; ++r) {
        acc[r] += __shfl_xor(acc[r], 16);
        acc[r] += __shfl_xor(acc[r], 32);
    }
#pragma unroll
    for (int off = 4; off < 64; off <<= 1) dacc += __shfl_xor(dacc, off);
    float d = bperm_f((li >> 2) << 2, dacc);

    if (lane < 16) {
        float inv = (row1 > row0) ? 1.f / d : 0.f;
        const float4* bv = (const float4*)bias + li * 2;
        float4 b0 = bv[0], b1 = bv[1];
        float o[8];
#pragma unroll
        for (int r = 0; r < 8; ++r) o[r] = acc[r] * inv;
        o[0] += b0.x; o[1] += b0.y; o[2] += b0.z; o[3] += b0.w;
        o[4] += b1.x; o[5] += b1.y; o[6] += b1.z; o[7] += b1.w;
        if (DOELU) {
#pragma unroll
            for (int r = 0; r < 8; ++r) o[r] = o[r] > 0.f ? o[r] : __expf(o[r]) - 1.f;
        }
        float4 q0, q1;
        q0.x = o[0]; q0.y = o[1]; q0.z = o[2]; q0.w = o[3];
        q1.x = o[4]; q1.y = o[5]; q1.z = o[6]; q1.w = o[7];
        float4* ov = (float4*)(out + (size_t)node * 128) + li * 2;
        ov[0] = q0;
        ov[1] = q1;
    }
}

// ---------------- aggregation (H=1, fp32 feat): one wave per dst node ----------------

__global__ __launch_bounds__(256) void agg1_kernel(const float* __restrict__ feat,
                                                   const float* __restrict__ el,
                                                   const float* __restrict__ er,
                                                   const int* __restrict__ rowptr,
                                                   const int* __restrict__ csrc,
                                                   const float* __restrict__ bias,
                                                   float* __restrict__ out, int N) {
    int lane = threadIdx.x & 63;
    int node = blockIdx.x * 4 + (threadIdx.x >> 6);
    if (node >= N) return;
    int row0 = __builtin_amdgcn_readfirstlane(rowptr[node]);
    int row1 = __builtin_amdgcn_readfirstlane(rowptr[node + 1]);

    float ern = er[node];
    int g = lane >> 3;
    int li = lane & 7;

    float dacc = 0.f;
    float acc[4];
#pragma unroll
    for (int r = 0; r < 4; ++r) acc[r] = 0.f;

    for (int base = row0; base < row1; base += 64) {
        int e = base + lane;
        int s = 0;
        float w0 = 0.f;
        if (e < row1) {
            s = csrc[e];
            float t0 = el[s] + ern;
            t0 = t0 > 0.f ? t0 : NEG_SLOPE * t0;
            w0 = __expf(t0);
            dacc += w0;
        }
        int cnt = min(row1 - base, 64);
        int iters = (cnt + 7) >> 3;
        int it = 0;
        for (; it + 1 < iters; it += 2) {
            int idxA = ((it << 3) + g) << 2;
            int idxB = (((it + 1) << 3) + g) << 2;
            int sjA = __builtin_amdgcn_ds_bpermute(idxA, s);
            float wA = bperm_f(idxA, w0);
            int sjB = __builtin_amdgcn_ds_bpermute(idxB, s);
            float wB = bperm_f(idxB, w0);
            const float4* fpA = (const float4*)(feat + (size_t)sjA * 32) + li;
            const float4* fpB = (const float4*)(feat + (size_t)sjB * 32) + li;
            float4 a0 = fpA[0], b0 = fpB[0];
            acc[0] = fmaf(wA, a0.x, acc[0]); acc[1] = fmaf(wA, a0.y, acc[1]);
            acc[2] = fmaf(wA, a0.z, acc[2]); acc[3] = fmaf(wA, a0.w, acc[3]);
            acc[0] = fmaf(wB, b0.x, acc[0]); acc[1] = fmaf(wB, b0.y, acc[1]);
            acc[2] = fmaf(wB, b0.z, acc[2]); acc[3] = fmaf(wB, b0.w, acc[3]);
        }
        if (it < iters) {
            int idx = ((it << 3) + g) << 2;
            int sj = __builtin_amdgcn_ds_bpermute(idx, s);
            float wsel = bperm_f(idx, w0);
            const float4* fp = (const float4*)(feat + (size_t)sj * 32) + li;
            float4 v0 = fp[0];
            acc[0] = fmaf(wsel, v0.x, acc[0]); acc[1] = fmaf(wsel, v0.y, acc[1]);
            acc[2] = fmaf(wsel, v0.z, acc[2]); acc[3] = fmaf(wsel, v0.w, acc[3]);
        }
    }

#pragma unroll
    for (int r = 0; r < 4; ++r) {
        acc[r] += __shfl_xor(acc[r], 8);
        acc[r] += __shfl_xor(acc[r], 16);
        acc[r] += __shfl_xor(acc[r], 32);
    }
#pragma unroll
    for (int off = 1; off < 64; off <<= 1) dacc += __shfl_xor(dacc, off);

    if (lane < 8) {
        float inv = (row1 > row0) ? 1.f / dacc : 0.f;
        float4 b0 = ((const float4*)bias)[lane];
        float4 q;
        q.x = acc[0] * inv + b0.x;
        q.y = acc[1] * inv + b0.y;
        q.z = acc[2] * inv + b0.z;
        q.w = acc[3] * inv + b0.w;
        ((float4*)(out + (size_t)node * 32))[lane] = q;
    }
}

// ---------------- host ----------------

extern "C" void kernel_launch(void* const* d_in, const int* in_sizes, int n_in,
                              void* d_out, int out_size, void* d_ws, size_t ws_size,
                              hipStream_t stream) {
    const float* features = (const float*)d_in[0];
    const int* esrc = (const int*)d_in[1];
    const int* edst = (const int*)d_in[2];
    const float* W1 = (const float*)d_in[3];
    const float* a1s = (const float*)d_in[4];
    const float* a1d = (const float*)d_in[5];
    const float* b1 = (const float*)d_in[6];
    const float* W2 = (const float*)d_in[7];
    const float* a2s = (const float*)d_in[8];
    const float* a2d = (const float*)d_in[9];
    const float* b2 = (const float*)d_in[10];
    const float* W3 = (const float*)d_in[11];
    const float* a3s = (const float*)d_in[12];
    const float* a3d = (const float*)d_in[13];
    const float* b3 = (const float*)d_in[14];

    int N = in_sizes[0] / 128;
    int E = in_sizes[1];
    int nb = (N + SCAN_CH - 1) / SCAN_CH;

    char* base = (char*)d_ws;
    size_t off = 0;
    auto nxt = [&](size_t bytes) {
        void* p = base + off;
        off += (bytes + 255) & ~(size_t)255;
        return p;
    };
    ushort* Yb = (ushort*)nxt((size_t)N * 128 * 2);  // bf16 feat (layers 1-2)
    float* B = (float*)nxt((size_t)N * 128 * 4);     // agg4 fp32 output
    float* A2 = (float*)nxt((size_t)N * 32 * 4);     // gemm32 fp32 output
    float* el = (float*)nxt((size_t)N * 4 * 4);
    float* er = (float*)nxt((size_t)N * 4 * 4);
    int* deg = (int*)nxt((size_t)N * 4);
    int* rowptr = (int*)nxt((size_t)(N + 1) * 4);
    int* csrc = (int*)nxt((size_t)E * 4);
    int* rank = (int*)nxt((size_t)E * 4);
    int* bsum = (int*)nxt((size_t)(nb + 1) * 4);
    int* boff = (int*)nxt((size_t)(nb + 1) * 4);

    // CSR build (same graph for all 3 layers)
    zero_ints<<<(N + 255) / 256, 256, 0, stream>>>(deg, N);
    hist_kernel<<<(E + 255) / 256, 256, 0, stream>>>(edst, deg, rank, E);
    scan_blocksum<<<nb, 256, 0, stream>>>(deg, bsum, N);
    scan_bsum<<<1, 64, 0, stream>>>(bsum, boff, nb);
    scan_write<<<nb, 256, 0, stream>>>(deg, boff, rowptr, N);
    fill_kernel<<<(E + 255) / 256, 256, 0, stream>>>(esrc, edst, rowptr, rank, csrc, E);

    // layer 1: 128 -> 4x32, ELU
    gemm_kernel<128, true><<<(N + 31) / 32, 256, 0, stream>>>(features, W1, nullptr, Yb,
                                                              a1s, a1d, el, er, N);
    agg4_kernel<true><<<(N + 3) / 4, 256, 0, stream>>>(Yb, el, er, rowptr, csrc, b1, B, N);

    // layer 2: 128 -> 4x32, ELU
    gemm_kernel<128, true><<<(N + 31) / 32, 256, 0, stream>>>(B, W2, nullptr, Yb,
                                                              a2s, a2d, el, er, N);
    agg4_kernel<true><<<(N + 3) / 4, 256, 0, stream>>>(Yb, el, er, rowptr, csrc, b2, B, N);

    // layer 3: 128 -> 1x32, no ELU, mean over 1 head = identity (fp32 path)
    gemm_kernel<32, false><<<(N + 127) / 128, 256, 0, stream>>>(B, W3, A2, nullptr,
                                                                a3s, a3d, el, er, N);
    agg1_kernel<<<(N + 3) / 4, 256, 0, stream>>>(A2, el, er, rowptr, csrc, b3,
                                                 (float*)d_out, N);
}

// Round 14
// 229.325 us; speedup vs baseline: 2.7328x; 1.1034x over previous
//
#include <hip/hip_runtime.h>

#define NEG_SLOPE 0.2f

typedef unsigned int uint;
typedef unsigned short ushort;
typedef __attribute__((ext_vector_type(8))) short bf16x8;
typedef __attribute__((ext_vector_type(4))) float f32x4;

__device__ __forceinline__ float bperm_f(int idx, float v) {
    return __int_as_float(__builtin_amdgcn_ds_bpermute(idx, __float_as_int(v)));
}

__device__ __forceinline__ uint pack_bf16x2(float a, float b) {
    uint ba = __float_as_uint(a);
    uint bb = __float_as_uint(b);
    uint ra = (ba + 0x7FFFu + ((ba >> 16) & 1u)) >> 16;
    uint rb = (bb + 0x7FFFu + ((bb >> 16) & 1u)) >> 16;
    return ra | (rb << 16);
}

__device__ __forceinline__ ushort bf16_rne(float v) {
    uint b = __float_as_uint(v);
    return (ushort)((b + 0x7FFFu + ((b >> 16) & 1u)) >> 16);
}

__device__ __forceinline__ void unpack_bf16x2(uint u, float& lo, float& hi) {
    lo = __uint_as_float(u << 16);
    hi = __uint_as_float(u & 0xFFFF0000u);
}

// ---------------- CSR build ----------------

__global__ void zero_ints(int* __restrict__ p, int n) {
    int i = blockIdx.x * 256 + threadIdx.x;
    if (i < n) p[i] = 0;
}

__global__ void hist_kernel(const int* __restrict__ dst, int* __restrict__ deg,
                            int* __restrict__ rank, int E) {
    int i = blockIdx.x * 256 + threadIdx.x;
    if (i < E) rank[i] = atomicAdd(&deg[dst[i]], 1);
}

#define SCAN_CH 2048

__global__ __launch_bounds__(256) void scan_blocksum(const int* __restrict__ deg,
                                                     int* __restrict__ bsum, int N) {
    int blk = blockIdx.x, t = threadIdx.x;
    int base = blk * SCAN_CH;
    int s = 0;
#pragma unroll
    for (int i = 0; i < SCAN_CH / 256; ++i) {
        int idx = base + t + i * 256;
        if (idx < N) s += deg[idx];
    }
#pragma unroll
    for (int off = 1; off < 64; off <<= 1) s += __shfl_xor(s, off);
    __shared__ int wt[4];
    if ((t & 63) == 0) wt[t >> 6] = s;
    __syncthreads();
    if (t == 0) bsum[blk] = wt[0] + wt[1] + wt[2] + wt[3];
}

__global__ void scan_bsum(const int* __restrict__ bsum, int* __restrict__ boff, int nb) {
    int t = threadIdx.x;
    int orig = (t < nb) ? bsum[t] : 0;
    int v = orig;
#pragma unroll
    for (int off = 1; off < 64; off <<= 1) {
        int u = __shfl_up(v, off);
        if (t >= off) v += u;
    }
    if (t < nb) boff[t] = v - orig;
}

__global__ __launch_bounds__(256) void scan_write(const int* __restrict__ deg,
                                                  const int* __restrict__ boff,
                                                  int* __restrict__ rowptr, int N) {
    int blk = blockIdx.x, t = threadIdx.x;
    int base = blk * SCAN_CH + t * 8;
    int v[8];
    int s = 0;
#pragma unroll
    for (int r = 0; r < 8; ++r) {
        int idx = base + r;
        v[r] = (idx < N) ? deg[idx] : 0;
        s += v[r];
    }
    int lane = t & 63, wid = t >> 6;
    int p = s;
#pragma unroll
    for (int off = 1; off < 64; off <<= 1) {
        int u = __shfl_up(p, off);
        if (lane >= off) p += u;
    }
    __shared__ int wtot[4];
    if (lane == 63) wtot[wid] = p;
    __syncthreads();
    int run = boff[blk];
    for (int w = 0; w < wid; ++w) run += wtot[w];
    run += p - s;
#pragma unroll
    for (int r = 0; r < 8; ++r) {
        int idx = base + r;
        if (idx < N) {
            rowptr[idx] = run;
            run += v[r];
            if (idx == N - 1) rowptr[N] = run;
        }
    }
}

__global__ void fill_kernel(const int* __restrict__ src, const int* __restrict__ dst,
                            const int* __restrict__ rowptr, const int* __restrict__ rank,
                            int* __restrict__ csrc, int E) {
    int i = blockIdx.x * 256 + threadIdx.x;
    if (i < E) {
        int d = dst[i];
        __builtin_nontemporal_store(src[i], csrc + rowptr[d] + rank[i]);
    }
}

// -------- fp32 -> bf16 conversion (8 elems/thread) --------

__global__ __launch_bounds__(256) void cvt_bf16_kernel(const float* __restrict__ X,
                                                       ushort* __restrict__ Xb, int n8) {
    int i = blockIdx.x * 256 + threadIdx.x;
    if (i >= n8) return;
    const float4* xp = (const float4*)X + (size_t)i * 2;
    float4 v0 = xp[0], v1 = xp[1];
    uint4 q;
    q.x = pack_bf16x2(v0.x, v0.y);
    q.y = pack_bf16x2(v0.z, v0.w);
    q.z = pack_bf16x2(v1.x, v1.y);
    q.w = pack_bf16x2(v1.z, v1.w);
    ((uint4*)Xb)[i] = q;
}

// -------- W -> MFMA B-fragment layout, bf16 --------
// frag[ct][kt][lane][j] = W[kt*32 + (lane>>4)*8 + j][ct*16 + (lane&15)]

template <int OUTF>
__global__ __launch_bounds__(256) void wpack_kernel(const float* __restrict__ W,
                                                    ushort* __restrict__ wfrag) {
    constexpr int TOT = (OUTF / 16) * 4 * 64;
    int idx = blockIdx.x * 256 + threadIdx.x;
    if (idx >= TOT) return;
    int lane = idx & 63;
    int kt = (idx >> 6) & 3;
    int ct = idx >> 8;
    int col = ct * 16 + (lane & 15);
    int k0 = kt * 32 + (lane >> 4) * 8;
    uint4 q;
    q.x = pack_bf16x2(W[(k0 + 0) * OUTF + col], W[(k0 + 1) * OUTF + col]);
    q.y = pack_bf16x2(W[(k0 + 2) * OUTF + col], W[(k0 + 3) * OUTF + col]);
    q.z = pack_bf16x2(W[(k0 + 4) * OUTF + col], W[(k0 + 5) * OUTF + col]);
    q.w = pack_bf16x2(W[(k0 + 6) * OUTF + col], W[(k0 + 7) * OUTF + col]);
    ((uint4*)wfrag)[idx] = q;
}

// -------- MFMA GEMM: Yb[N,OUTF] (bf16) = Xb[N,128] @ W + fused el/er (fp32 acc) --------
// 4 waves/block, wave = 16 rows; C/D layout: col=lane&15, row=(lane>>4)*4+j (m89)

template <int OUTF>
__global__ __launch_bounds__(256) void gemm_mfma_kernel(const ushort* __restrict__ Xb,
                                                        const ushort* __restrict__ wfrag,
                                                        ushort* __restrict__ Yb,
                                                        const float* __restrict__ as_,
                                                        const float* __restrict__ ad_,
                                                        float* __restrict__ el,
                                                        float* __restrict__ er, int N) {
    constexpr int H = OUTF / 32;
    constexpr int NCT = OUTF / 16;
    int lane = threadIdx.x & 63;
    int wv = threadIdx.x >> 6;
    int r0 = blockIdx.x * 64 + wv * 16;
    if (r0 >= N) return;
    int lrow = lane & 15;
    int lk8 = lane >> 4;

    bf16x8 afrag[4];
    {
        int arow = min(r0 + lrow, N - 1);
        const ushort* xr = Xb + (size_t)arow * 128;
#pragma unroll
        for (int kt = 0; kt < 4; ++kt)
            afrag[kt] = *(const bf16x8*)(xr + kt * 32 + lk8 * 8);
    }

    float pel[H][4];
    float prr[H][4];
#pragma unroll
    for (int h = 0; h < H; ++h)
#pragma unroll
        for (int j = 0; j < 4; ++j) { pel[h][j] = 0.f; prr[h][j] = 0.f; }

    const bf16x8* wf = (const bf16x8*)wfrag;
#pragma unroll
    for (int ct = 0; ct < NCT; ++ct) {
        f32x4 acc = {0.f, 0.f, 0.f, 0.f};
#pragma unroll
        for (int kt = 0; kt < 4; ++kt) {
            bf16x8 b = wf[(ct * 4 + kt) * 64 + lane];
            acc = __builtin_amdgcn_mfma_f32_16x16x32_bf16(afrag[kt], b, acc, 0, 0, 0);
        }
        int col = ct * 16 + lrow;
        constexpr int hh = 0;  // placeholder; real head below (compile-time)
        int h = (H == 1) ? 0 : (ct >> 1);
        float asc = as_[col], adc = ad_[col];
#pragma unroll
        for (int j = 0; j < 4; ++j) {
            int row = r0 + lk8 * 4 + j;
            float v = acc[j];
            if (row < N) Yb[(size_t)row * OUTF + col] = bf16_rne(v);
            pel[h][j] = fmaf(v, asc, pel[h][j]);
            prr[h][j] = fmaf(v, adc, prr[h][j]);
        }
        (void)hh;
    }

#pragma unroll
    for (int h = 0; h < H; ++h)
#pragma unroll
        for (int j = 0; j < 4; ++j) {
            float pe = pel[h][j], pr = prr[h][j];
#pragma unroll
            for (int off = 1; off < 16; off <<= 1) {
                pe += __shfl_xor(pe, off);
                pr += __shfl_xor(pr, off);
            }
            if (lrow == 0) {
                int row = r0 + lk8 * 4 + j;
                if (row < N) {
                    el[row * H + h] = pe;
                    er[row * H + h] = pr;
                }
            }
        }
}

// ---------------- aggregation (H=4, bf16 feat -> bf16 out) ----------------

template <bool DOELU>
__global__ __launch_bounds__(256) void agg4_kernel(const ushort* __restrict__ featb,
                                                   const float* __restrict__ el,
                                                   const float* __restrict__ er,
                                                   const int* __restrict__ rowptr,
                                                   const int* __restrict__ csrc,
                                                   const float* __restrict__ bias,
                                                   ushort* __restrict__ outb, int N) {
    int lane = threadIdx.x & 63;
    int node = blockIdx.x * 4 + (threadIdx.x >> 6);
    if (node >= N) return;
    int row0 = __builtin_amdgcn_readfirstlane(rowptr[node]);
    int row1 = __builtin_amdgcn_readfirstlane(rowptr[node + 1]);

    int qe = lane >> 2;
    int qh = lane & 3;
    float ern = er[node * 4 + qh];

    int g = lane >> 4;
    int li = lane & 15;
    int h = li >> 2;
    int ib = (g << 4) + (h << 2);

    float dacc = 0.f;
    float acc[8];
#pragma unroll
    for (int r = 0; r < 8; ++r) acc[r] = 0.f;

    for (int base = row0; base < row1; base += 16) {
        int e = base + qe;
        int s = 0;
        float w = 0.f;
        if (e < row1) {
            s = csrc[e];
            float tt = el[s * 4 + qh] + ern;
            tt = tt > 0.f ? tt : NEG_SLOPE * tt;
            w = __expf(tt);
            dacc += w;
        }
        int sj0 = __builtin_amdgcn_ds_bpermute(ib, s);
        float w0 = bperm_f(ib, w);
        int sj1 = __builtin_amdgcn_ds_bpermute(ib + 64, s);
        float w1 = bperm_f(ib + 64, w);
        int sj2 = __builtin_amdgcn_ds_bpermute(ib + 128, s);
        float w2 = bperm_f(ib + 128, w);
        int sj3 = __builtin_amdgcn_ds_bpermute(ib + 192, s);
        float w3 = bperm_f(ib + 192, w);
        uint4 U0 = *(const uint4*)(featb + (size_t)sj0 * 128 + li * 8);
        uint4 U1 = *(const uint4*)(featb + (size_t)sj1 * 128 + li * 8);
        uint4 U2 = *(const uint4*)(featb + (size_t)sj2 * 128 + li * 8);
        uint4 U3 = *(const uint4*)(featb + (size_t)sj3 * 128 + li * 8);
        float f0, f1, f2, f3, f4, f5, f6, f7;
        unpack_bf16x2(U0.x, f0, f1); unpack_bf16x2(U0.y, f2, f3);
        unpack_bf16x2(U0.z, f4, f5); unpack_bf16x2(U0.w, f6, f7);
        acc[0] = fmaf(w0, f0, acc[0]); acc[1] = fmaf(w0, f1, acc[1]);
        acc[2] = fmaf(w0, f2, acc[2]); acc[3] = fmaf(w0, f3, acc[3]);
        acc[4] = fmaf(w0, f4, acc[4]); acc[5] = fmaf(w0, f5, acc[5]);
        acc[6] = fmaf(w0, f6, acc[6]); acc[7] = fmaf(w0, f7, acc[7]);
        unpack_bf16x2(U1.x, f0, f1); unpack_bf16x2(U1.y, f2, f3);
        unpack_bf16x2(U1.z, f4, f5); unpack_bf16x2(U1.w, f6, f7);
        acc[0] = fmaf(w1, f0, acc[0]); acc[1] = fmaf(w1, f1, acc[1]);
        acc[2] = fmaf(w1, f2, acc[2]); acc[3] = fmaf(w1, f3, acc[3]);
        acc[4] = fmaf(w1, f4, acc[4]); acc[5] = fmaf(w1, f5, acc[5]);
        acc[6] = fmaf(w1, f6, acc[6]); acc[7] = fmaf(w1, f7, acc[7]);
        unpack_bf16x2(U2.x, f0, f1); unpack_bf16x2(U2.y, f2, f3);
        unpack_bf16x2(U2.z, f4, f5); unpack_bf16x2(U2.w, f6, f7);
        acc[0] = fmaf(w2, f0, acc[0]); acc[1] = fmaf(w2, f1, acc[1]);
        acc[2] = fmaf(w2, f2, acc[2]); acc[3] = fmaf(w2, f3, acc[3]);
        acc[4] = fmaf(w2, f4, acc[4]); acc[5] = fmaf(w2, f5, acc[5]);
        acc[6] = fmaf(w2, f6, acc[6]); acc[7] = fmaf(w2, f7, acc[7]);
        unpack_bf16x2(U3.x, f0, f1); unpack_bf16x2(U3.y, f2, f3);
        unpack_bf16x2(U3.z, f4, f5); unpack_bf16x2(U3.w, f6, f7);
        acc[0] = fmaf(w3, f0, acc[0]); acc[1] = fmaf(w3, f1, acc[1]);
        acc[2] = fmaf(w3, f2, acc[2]); acc[3] = fmaf(w3, f3, acc[3]);
        acc[4] = fmaf(w3, f4, acc[4]); acc[5] = fmaf(w3, f5, acc[5]);
        acc[6] = fmaf(w3, f6, acc[6]); acc[7] = fmaf(w3, f7, acc[7]);
    }

#pragma unroll
    for (int r = 0; r < 8; ++r) {
        acc[r] += __shfl_xor(acc[r], 16);
        acc[r] += __shfl_xor(acc[r], 32);
    }
#pragma unroll
    for (int off = 4; off < 64; off <<= 1) dacc += __shfl_xor(dacc, off);
    float d = bperm_f((li >> 2) << 2, dacc);

    if (lane < 16) {
        float inv = (row1 > row0) ? 1.f / d : 0.f;
        const float4* bv = (const float4*)bias + li * 2;
        float4 b0 = bv[0], b1 = bv[1];
        float o[8];
#pragma unroll
        for (int r = 0; r < 8; ++r) o[r] = acc[r] * inv;
        o[0] += b0.x; o[1] += b0.y; o[2] += b0.z; o[3] += b0.w;
        o[4] += b1.x; o[5] += b1.y; o[6] += b1.z; o[7] += b1.w;
        if (DOELU) {
#pragma unroll
            for (int r = 0; r < 8; ++r) o[r] = o[r] > 0.f ? o[r] : __expf(o[r]) - 1.f;
        }
        uint4 q;
        q.x = pack_bf16x2(o[0], o[1]);
        q.y = pack_bf16x2(o[2], o[3]);
        q.z = pack_bf16x2(o[4], o[5]);
        q.w = pack_bf16x2(o[6], o[7]);
        *(uint4*)(outb + (size_t)node * 128 + li * 8) = q;
    }
}

// ---------------- aggregation (H=1, bf16 feat -> fp32 out) ----------------

__global__ __launch_bounds__(256) void agg1_kernel(const ushort* __restrict__ featb,
                                                   const float* __restrict__ el,
                                                   const float* __restrict__ er,
                                                   const int* __restrict__ rowptr,
                                                   const int* __restrict__ csrc,
                                                   const float* __restrict__ bias,
                                                   float* __restrict__ out, int N) {
    int lane = threadIdx.x & 63;
    int node = blockIdx.x * 4 + (threadIdx.x >> 6);
    if (node >= N) return;
    int row0 = __builtin_amdgcn_readfirstlane(rowptr[node]);
    int row1 = __builtin_amdgcn_readfirstlane(rowptr[node + 1]);

    float ern = er[node];
    int g = lane >> 3;
    int li = lane & 7;

    float dacc = 0.f;
    float acc[4];
#pragma unroll
    for (int r = 0; r < 4; ++r) acc[r] = 0.f;

    for (int base = row0; base < row1; base += 64) {
        int e = base + lane;
        int s = 0;
        float w0 = 0.f;
        if (e < row1) {
            s = csrc[e];
            float t0 = el[s] + ern;
            t0 = t0 > 0.f ? t0 : NEG_SLOPE * t0;
            w0 = __expf(t0);
            dacc += w0;
        }
        int cnt = min(row1 - base, 64);
        int iters = (cnt + 7) >> 3;
        int it = 0;
        for (; it + 1 < iters; it += 2) {
            int idxA = ((it << 3) + g) << 2;
            int idxB = (((it + 1) << 3) + g) << 2;
            int sjA = __builtin_amdgcn_ds_bpermute(idxA, s);
            float wA = bperm_f(idxA, w0);
            int sjB = __builtin_amdgcn_ds_bpermute(idxB, s);
            float wB = bperm_f(idxB, w0);
            uint2 UA = *(const uint2*)(featb + (size_t)sjA * 32 + li * 4);
            uint2 UB = *(const uint2*)(featb + (size_t)sjB * 32 + li * 4);
            float f0, f1, f2, f3;
            unpack_bf16x2(UA.x, f0, f1); unpack_bf16x2(UA.y, f2, f3);
            acc[0] = fmaf(wA, f0, acc[0]); acc[1] = fmaf(wA, f1, acc[1]);
            acc[2] = fmaf(wA, f2, acc[2]); acc[3] = fmaf(wA, f3, acc[3]);
            unpack_bf16x2(UB.x, f0, f1); unpack_bf16x2(UB.y, f2, f3);
            acc[0] = fmaf(wB, f0, acc[0]); acc[1] = fmaf(wB, f1, acc[1]);
            acc[2] = fmaf(wB, f2, acc[2]); acc[3] = fmaf(wB, f3, acc[3]);
        }
        if (it < iters) {
            int idx = ((it << 3) + g) << 2;
            int sj = __builtin_amdgcn_ds_bpermute(idx, s);
            float wsel = bperm_f(idx, w0);
            uint2 U = *(const uint2*)(featb + (size_t)sj * 32 + li * 4);
            float f0, f1, f2, f3;
            unpack_bf16x2(U.x, f0, f1); unpack_bf16x2(U.y, f2, f3);
            acc[0] = fmaf(wsel, f0, acc[0]); acc[1] = fmaf(wsel, f1, acc[1]);
            acc[2] = fmaf(wsel, f2, acc[2]); acc[3] = fmaf(wsel, f3, acc[3]);
        }
    }

#pragma unroll
    for (int r = 0; r < 4; ++r) {
        acc[r] += __shfl_xor(acc[r], 8);
        acc[r] += __shfl_xor(acc[r], 16);
        acc[r] += __shfl_xor(acc[r], 32);
    }
#pragma unroll
    for (int off = 1; off < 64; off <<= 1) dacc += __shfl_xor(dacc, off);

    if (lane < 8) {
        float inv = (row1 > row0) ? 1.f / dacc : 0.f;
        float4 b0 = ((const float4*)bias)[lane];
        float4 q;
        q.x = acc[0] * inv + b0.x;
        q.y = acc[1] * inv + b0.y;
        q.z = acc[2] * inv + b0.z;
        q.w = acc[3] * inv + b0.w;
        ((float4*)(out + (size_t)node * 32))[lane] = q;
    }
}

// ---------------- host ----------------

extern "C" void kernel_launch(void* const* d_in, const int* in_sizes, int n_in,
                              void* d_out, int out_size, void* d_ws, size_t ws_size,
                              hipStream_t stream) {
    const float* features = (const float*)d_in[0];
    const int* esrc = (const int*)d_in[1];
    const int* edst = (const int*)d_in[2];
    const float* W1 = (const float*)d_in[3];
    const float* a1s = (const float*)d_in[4];
    const float* a1d = (const float*)d_in[5];
    const float* b1 = (const float*)d_in[6];
    const float* W2 = (const float*)d_in[7];
    const float* a2s = (const float*)d_in[8];
    const float* a2d = (const float*)d_in[9];
    const float* b2 = (const float*)d_in[10];
    const float* W3 = (const float*)d_in[11];
    const float* a3s = (const float*)d_in[12];
    const float* a3d = (const float*)d_in[13];
    const float* b3 = (const float*)d_in[14];

    int N = in_sizes[0] / 128;
    int E = in_sizes[1];
    int nb = (N + SCAN_CH - 1) / SCAN_CH;

    char* base = (char*)d_ws;
    size_t off = 0;
    auto nxt = [&](size_t bytes) {
        void* p = base + off;
        off += (bytes + 255) & ~(size_t)255;
        return p;
    };
    ushort* Xb = (ushort*)nxt((size_t)N * 128 * 2);   // bf16 features (layer-1 input)
    ushort* Yb = (ushort*)nxt((size_t)N * 128 * 2);   // gemm out / agg4 in
    ushort* Bb = (ushort*)nxt((size_t)N * 128 * 2);   // agg4 out / gemm in
    ushort* Y3b = (ushort*)nxt((size_t)N * 32 * 2);   // gemm32 out
    float* el = (float*)nxt((size_t)N * 4 * 4);
    float* er = (float*)nxt((size_t)N * 4 * 4);
    int* deg = (int*)nxt((size_t)N * 4);
    int* rowptr = (int*)nxt((size_t)(N + 1) * 4);
    int* csrc = (int*)nxt((size_t)E * 4);
    int* rank = (int*)nxt((size_t)E * 4);
    int* bsum = (int*)nxt((size_t)(nb + 1) * 4);
    int* boff = (int*)nxt((size_t)(nb + 1) * 4);
    ushort* wf1 = (ushort*)nxt(16384 * 2);
    ushort* wf2 = (ushort*)nxt(16384 * 2);
    ushort* wf3 = (ushort*)nxt(4096 * 2);

    int gemm_grid = (N + 63) / 64;

    // CSR build + input conversions (independent)
    zero_ints<<<(N + 255) / 256, 256, 0, stream>>>(deg, N);
    hist_kernel<<<(E + 255) / 256, 256, 0, stream>>>(edst, deg, rank, E);
    cvt_bf16_kernel<<<(N * 16 + 255) / 256, 256, 0, stream>>>(features, Xb, N * 16);
    wpack_kernel<128><<<8, 256, 0, stream>>>(W1, wf1);
    wpack_kernel<128><<<8, 256, 0, stream>>>(W2, wf2);
    wpack_kernel<32><<<2, 256, 0, stream>>>(W3, wf3);
    scan_blocksum<<<nb, 256, 0, stream>>>(deg, bsum, N);
    scan_bsum<<<1, 64, 0, stream>>>(bsum, boff, nb);
    scan_write<<<nb, 256, 0, stream>>>(deg, boff, rowptr, N);
    fill_kernel<<<(E + 255) / 256, 256, 0, stream>>>(esrc, edst, rowptr, rank, csrc, E);

    // layer 1: 128 -> 4x32, ELU
    gemm_mfma_kernel<128><<<gemm_grid, 256, 0, stream>>>(Xb, wf1, Yb, a1s, a1d, el, er, N);
    agg4_kernel<true><<<(N + 3) / 4, 256, 0, stream>>>(Yb, el, er, rowptr, csrc, b1, Bb, N);

    // layer 2: 128 -> 4x32, ELU
    gemm_mfma_kernel<128><<<gemm_grid, 256, 0, stream>>>(Bb, wf2, Yb, a2s, a2d, el, er, N);
    agg4_kernel<true><<<(N + 3) / 4, 256, 0, stream>>>(Yb, el, er, rowptr, csrc, b2, Bb, N);

    // layer 3: 128 -> 1x32, no ELU, mean over 1 head = identity
    gemm_mfma_kernel<32><<<gemm_grid, 256, 0, stream>>>(Bb, wf3, Y3b, a3s, a3d, el, er, N);
    agg1_kernel<<<(N + 3) / 4, 256, 0, stream>>>(Y3b, el, er, rowptr, csrc, b3,
                                                 (float*)d_out, N);
}

// Round 15
// 225.688 us; speedup vs baseline: 2.7768x; 1.0161x over previous
//
#include <hip/hip_runtime.h>
#include <hip/hip_fp16.h>

#define NEG_SLOPE 0.2f

typedef unsigned int uint;
typedef unsigned short ushort;
typedef __attribute__((ext_vector_type(8))) short bf16x8;
typedef __attribute__((ext_vector_type(4))) float f32x4;
typedef __attribute__((ext_vector_type(2))) float f32x2;

__device__ __forceinline__ uint pack_bf16x2(float a, float b) {
    uint ba = __float_as_uint(a);
    uint bb = __float_as_uint(b);
    uint ra = (ba + 0x7FFFu + ((ba >> 16) & 1u)) >> 16;
    uint rb = (bb + 0x7FFFu + ((bb >> 16) & 1u)) >> 16;
    return ra | (rb << 16);
}

__device__ __forceinline__ ushort bf16_rne(float v) {
    uint b = __float_as_uint(v);
    return (ushort)((b + 0x7FFFu + ((b >> 16) & 1u)) >> 16);
}

// unpack one u32 of 2 bf16 into a float2 (lo, hi)
__device__ __forceinline__ f32x2 unpack2(uint u) {
    f32x2 r;
    r.x = __uint_as_float(u << 16);
    r.y = __uint_as_float(u & 0xFFFF0000u);
    return r;
}

// pack (src_id, fp16 weight) into one dword for single-bpermute broadcast
__device__ __forceinline__ uint pack_sw(int s, float w) {
    return ((uint)s << 16) | (uint)__half_as_ushort(__float2half_rn(w));
}

__device__ __forceinline__ int sw_src(uint u) { return (int)(u >> 16); }
__device__ __forceinline__ float sw_w(uint u) {
    return __half2float(__ushort_as_half((ushort)(u & 0xFFFFu)));
}

// ---------------- CSR build ----------------

__global__ void zero_ints(int* __restrict__ p, int n) {
    int i = blockIdx.x * 256 + threadIdx.x;
    if (i < n) p[i] = 0;
}

__global__ void hist_kernel(const int* __restrict__ dst, int* __restrict__ deg,
                            int* __restrict__ rank, int E) {
    int i = blockIdx.x * 256 + threadIdx.x;
    if (i < E) rank[i] = atomicAdd(&deg[dst[i]], 1);
}

#define SCAN_CH 2048

__global__ __launch_bounds__(256) void scan_blocksum(const int* __restrict__ deg,
                                                     int* __restrict__ bsum, int N) {
    int blk = blockIdx.x, t = threadIdx.x;
    int base = blk * SCAN_CH;
    int s = 0;
#pragma unroll
    for (int i = 0; i < SCAN_CH / 256; ++i) {
        int idx = base + t + i * 256;
        if (idx < N) s += deg[idx];
    }
#pragma unroll
    for (int off = 1; off < 64; off <<= 1) s += __shfl_xor(s, off);
    __shared__ int wt[4];
    if ((t & 63) == 0) wt[t >> 6] = s;
    __syncthreads();
    if (t == 0) bsum[blk] = wt[0] + wt[1] + wt[2] + wt[3];
}

__global__ void scan_bsum(const int* __restrict__ bsum, int* __restrict__ boff, int nb) {
    int t = threadIdx.x;
    int orig = (t < nb) ? bsum[t] : 0;
    int v = orig;
#pragma unroll
    for (int off = 1; off < 64; off <<= 1) {
        int u = __shfl_up(v, off);
        if (t >= off) v += u;
    }
    if (t < nb) boff[t] = v - orig;
}

__global__ __launch_bounds__(256) void scan_write(const int* __restrict__ deg,
                                                  const int* __restrict__ boff,
                                                  int* __restrict__ rowptr, int N) {
    int blk = blockIdx.x, t = threadIdx.x;
    int base = blk * SCAN_CH + t * 8;
    int v[8];
    int s = 0;
#pragma unroll
    for (int r = 0; r < 8; ++r) {
        int idx = base + r;
        v[r] = (idx < N) ? deg[idx] : 0;
        s += v[r];
    }
    int lane = t & 63, wid = t >> 6;
    int p = s;
#pragma unroll
    for (int off = 1; off < 64; off <<= 1) {
        int u = __shfl_up(p, off);
        if (lane >= off) p += u;
    }
    __shared__ int wtot[4];
    if (lane == 63) wtot[wid] = p;
    __syncthreads();
    int run = boff[blk];
    for (int w = 0; w < wid; ++w) run += wtot[w];
    run += p - s;
#pragma unroll
    for (int r = 0; r < 8; ++r) {
        int idx = base + r;
        if (idx < N) {
            rowptr[idx] = run;
            run += v[r];
            if (idx == N - 1) rowptr[N] = run;
        }
    }
}

__global__ void fill_kernel(const int* __restrict__ src, const int* __restrict__ dst,
                            const int* __restrict__ rowptr, const int* __restrict__ rank,
                            int* __restrict__ csrc, int E) {
    int i = blockIdx.x * 256 + threadIdx.x;
    if (i < E) {
        int d = dst[i];
        __builtin_nontemporal_store(src[i], csrc + rowptr[d] + rank[i]);
    }
}

// -------- fp32 -> bf16 conversion (8 elems/thread) --------

__global__ __launch_bounds__(256) void cvt_bf16_kernel(const float* __restrict__ X,
                                                       ushort* __restrict__ Xb, int n8) {
    int i = blockIdx.x * 256 + threadIdx.x;
    if (i >= n8) return;
    const float4* xp = (const float4*)X + (size_t)i * 2;
    float4 v0 = xp[0], v1 = xp[1];
    uint4 q;
    q.x = pack_bf16x2(v0.x, v0.y);
    q.y = pack_bf16x2(v0.z, v0.w);
    q.z = pack_bf16x2(v1.x, v1.y);
    q.w = pack_bf16x2(v1.z, v1.w);
    ((uint4*)Xb)[i] = q;
}

// -------- W -> MFMA B-fragment layout, bf16 --------

template <int OUTF>
__global__ __launch_bounds__(256) void wpack_kernel(const float* __restrict__ W,
                                                    ushort* __restrict__ wfrag) {
    constexpr int TOT = (OUTF / 16) * 4 * 64;
    int idx = blockIdx.x * 256 + threadIdx.x;
    if (idx >= TOT) return;
    int lane = idx & 63;
    int kt = (idx >> 6) & 3;
    int ct = idx >> 8;
    int col = ct * 16 + (lane & 15);
    int k0 = kt * 32 + (lane >> 4) * 8;
    uint4 q;
    q.x = pack_bf16x2(W[(k0 + 0) * OUTF + col], W[(k0 + 1) * OUTF + col]);
    q.y = pack_bf16x2(W[(k0 + 2) * OUTF + col], W[(k0 + 3) * OUTF + col]);
    q.z = pack_bf16x2(W[(k0 + 4) * OUTF + col], W[(k0 + 5) * OUTF + col]);
    q.w = pack_bf16x2(W[(k0 + 6) * OUTF + col], W[(k0 + 7) * OUTF + col]);
    ((uint4*)wfrag)[idx] = q;
}

// -------- MFMA GEMM: Yb[N,OUTF] (bf16) = Xb[N,128] @ W + fused el/er --------

template <int OUTF>
__global__ __launch_bounds__(256) void gemm_mfma_kernel(const ushort* __restrict__ Xb,
                                                        const ushort* __restrict__ wfrag,
                                                        ushort* __restrict__ Yb,
                                                        const float* __restrict__ as_,
                                                        const float* __restrict__ ad_,
                                                        float* __restrict__ el,
                                                        float* __restrict__ er, int N) {
    constexpr int H = OUTF / 32;
    constexpr int NCT = OUTF / 16;
    int lane = threadIdx.x & 63;
    int wv = threadIdx.x >> 6;
    int r0 = blockIdx.x * 64 + wv * 16;
    if (r0 >= N) return;
    int lrow = lane & 15;
    int lk8 = lane >> 4;

    bf16x8 afrag[4];
    {
        int arow = min(r0 + lrow, N - 1);
        const ushort* xr = Xb + (size_t)arow * 128;
#pragma unroll
        for (int kt = 0; kt < 4; ++kt)
            afrag[kt] = *(const bf16x8*)(xr + kt * 32 + lk8 * 8);
    }

    float pel[H][4];
    float prr[H][4];
#pragma unroll
    for (int h = 0; h < H; ++h)
#pragma unroll
        for (int j = 0; j < 4; ++j) { pel[h][j] = 0.f; prr[h][j] = 0.f; }

    const bf16x8* wf = (const bf16x8*)wfrag;
#pragma unroll
    for (int ct = 0; ct < NCT; ++ct) {
        f32x4 acc = {0.f, 0.f, 0.f, 0.f};
#pragma unroll
        for (int kt = 0; kt < 4; ++kt) {
            bf16x8 b = wf[(ct * 4 + kt) * 64 + lane];
            acc = __builtin_amdgcn_mfma_f32_16x16x32_bf16(afrag[kt], b, acc, 0, 0, 0);
        }
        int col = ct * 16 + lrow;
        int h = (H == 1) ? 0 : (ct >> 1);
        float asc = as_[col], adc = ad_[col];
#pragma unroll
        for (int j = 0; j < 4; ++j) {
            int row = r0 + lk8 * 4 + j;
            float v = acc[j];
            if (row < N) Yb[(size_t)row * OUTF + col] = bf16_rne(v);
            pel[h][j] = fmaf(v, asc, pel[h][j]);
            prr[h][j] = fmaf(v, adc, prr[h][j]);
        }
    }

#pragma unroll
    for (int h = 0; h < H; ++h)
#pragma unroll
        for (int j = 0; j < 4; ++j) {
            float pe = pel[h][j], pr = prr[h][j];
#pragma unroll
            for (int off = 1; off < 16; off <<= 1) {
                pe += __shfl_xor(pe, off);
                pr += __shfl_xor(pr, off);
            }
            if (lrow == 0) {
                int row = r0 + lk8 * 4 + j;
                if (row < N) {
                    el[row * H + h] = pe;
                    er[row * H + h] = pr;
                }
            }
        }
}

// ---------------- aggregation (H=4, bf16 feat -> bf16 out) ----------------
// Weight phase: lane m = (edge m>>2, head m&3); packs (src<<16 | fp16(w)).
// Gather: 1 bpermute/slot; f32x2 packed fma accumulation.

template <bool DOELU>
__global__ __launch_bounds__(256) void agg4_kernel(const ushort* __restrict__ featb,
                                                   const float* __restrict__ el,
                                                   const float* __restrict__ er,
                                                   const int* __restrict__ rowptr,
                                                   const int* __restrict__ csrc,
                                                   const float* __restrict__ bias,
                                                   ushort* __restrict__ outb, int N) {
    int lane = threadIdx.x & 63;
    int node = blockIdx.x * 4 + (threadIdx.x >> 6);
    if (node >= N) return;
    int row0 = __builtin_amdgcn_readfirstlane(rowptr[node]);
    int row1 = __builtin_amdgcn_readfirstlane(rowptr[node + 1]);

    int qe = lane >> 2;
    int qh = lane & 3;
    float ern = er[node * 4 + qh];

    int g = lane >> 4;
    int li = lane & 15;
    int h = li >> 2;
    int ib = (g << 4) + (h << 2);  // byte addr of lane (g*4+h), iter 0

    float dacc = 0.f;
    f32x2 acc2[4];
#pragma unroll
    for (int r = 0; r < 4; ++r) acc2[r] = (f32x2){0.f, 0.f};

    for (int base = row0; base < row1; base += 16) {
        int e = base + qe;
        uint u = 0;
        if (e < row1) {
            int s = csrc[e];
            float tt = el[s * 4 + qh] + ern;
            tt = tt > 0.f ? tt : NEG_SLOPE * tt;
            float w = __expf(tt);
            dacc += w;
            u = pack_sw(s, w);
        }
        uint u0 = (uint)__builtin_amdgcn_ds_bpermute(ib, (int)u);
        uint u1 = (uint)__builtin_amdgcn_ds_bpermute(ib + 64, (int)u);
        uint u2 = (uint)__builtin_amdgcn_ds_bpermute(ib + 128, (int)u);
        uint u3 = (uint)__builtin_amdgcn_ds_bpermute(ib + 192, (int)u);
        uint4 U0 = *(const uint4*)(featb + (size_t)sw_src(u0) * 128 + li * 8);
        uint4 U1 = *(const uint4*)(featb + (size_t)sw_src(u1) * 128 + li * 8);
        uint4 U2 = *(const uint4*)(featb + (size_t)sw_src(u2) * 128 + li * 8);
        uint4 U3 = *(const uint4*)(featb + (size_t)sw_src(u3) * 128 + li * 8);
        float w0 = sw_w(u0), w1 = sw_w(u1), w2 = sw_w(u2), w3 = sw_w(u3);
        acc2[0] = unpack2(U0.x) * w0 + acc2[0];
        acc2[1] = unpack2(U0.y) * w0 + acc2[1];
        acc2[2] = unpack2(U0.z) * w0 + acc2[2];
        acc2[3] = unpack2(U0.w) * w0 + acc2[3];
        acc2[0] = unpack2(U1.x) * w1 + acc2[0];
        acc2[1] = unpack2(U1.y) * w1 + acc2[1];
        acc2[2] = unpack2(U1.z) * w1 + acc2[2];
        acc2[3] = unpack2(U1.w) * w1 + acc2[3];
        acc2[0] = unpack2(U2.x) * w2 + acc2[0];
        acc2[1] = unpack2(U2.y) * w2 + acc2[1];
        acc2[2] = unpack2(U2.z) * w2 + acc2[2];
        acc2[3] = unpack2(U2.w) * w2 + acc2[3];
        acc2[0] = unpack2(U3.x) * w3 + acc2[0];
        acc2[1] = unpack2(U3.y) * w3 + acc2[1];
        acc2[2] = unpack2(U3.z) * w3 + acc2[2];
        acc2[3] = unpack2(U3.w) * w3 + acc2[3];
    }

#pragma unroll
    for (int r = 0; r < 4; ++r) {
        acc2[r].x += __shfl_xor(acc2[r].x, 16);
        acc2[r].y += __shfl_xor(acc2[r].y, 16);
        acc2[r].x += __shfl_xor(acc2[r].x, 32);
        acc2[r].y += __shfl_xor(acc2[r].y, 32);
    }
#pragma unroll
    for (int off = 4; off < 64; off <<= 1) dacc += __shfl_xor(dacc, off);
    // head denom lives on lanes with qh == li>>2; pull from lane ((li>>2)) via bpermute
    float d = __int_as_float(
        __builtin_amdgcn_ds_bpermute((li >> 2) << 2, __float_as_int(dacc)));

    if (lane < 16) {
        float inv = (row1 > row0) ? 1.f / d : 0.f;
        const float4* bv = (const float4*)bias + li * 2;
        float4 b0 = bv[0], b1 = bv[1];
        float o[8];
        o[0] = acc2[0].x * inv + b0.x;
        o[1] = acc2[0].y * inv + b0.y;
        o[2] = acc2[1].x * inv + b0.z;
        o[3] = acc2[1].y * inv + b0.w;
        o[4] = acc2[2].x * inv + b1.x;
        o[5] = acc2[2].y * inv + b1.y;
        o[6] = acc2[3].x * inv + b1.z;
        o[7] = acc2[3].y * inv + b1.w;
        if (DOELU) {
#pragma unroll
            for (int r = 0; r < 8; ++r) o[r] = o[r] > 0.f ? o[r] : __expf(o[r]) - 1.f;
        }
        uint4 q;
        q.x = pack_bf16x2(o[0], o[1]);
        q.y = pack_bf16x2(o[2], o[3]);
        q.z = pack_bf16x2(o[4], o[5]);
        q.w = pack_bf16x2(o[6], o[7]);
        *(uint4*)(outb + (size_t)node * 128 + li * 8) = q;
    }
}

// ---------------- aggregation (H=1, bf16 feat -> fp32 out) ----------------

__global__ __launch_bounds__(256) void agg1_kernel(const ushort* __restrict__ featb,
                                                   const float* __restrict__ el,
                                                   const float* __restrict__ er,
                                                   const int* __restrict__ rowptr,
                                                   const int* __restrict__ csrc,
                                                   const float* __restrict__ bias,
                                                   float* __restrict__ out, int N) {
    int lane = threadIdx.x & 63;
    int node = blockIdx.x * 4 + (threadIdx.x >> 6);
    if (node >= N) return;
    int row0 = __builtin_amdgcn_readfirstlane(rowptr[node]);
    int row1 = __builtin_amdgcn_readfirstlane(rowptr[node + 1]);

    float ern = er[node];
    int g = lane >> 3;
    int li = lane & 7;

    float dacc = 0.f;
    f32x2 acc2[2];
    acc2[0] = (f32x2){0.f, 0.f};
    acc2[1] = (f32x2){0.f, 0.f};

    for (int base = row0; base < row1; base += 64) {
        int e = base + lane;
        uint u = 0;
        if (e < row1) {
            int s = csrc[e];
            float t0 = el[s] + ern;
            t0 = t0 > 0.f ? t0 : NEG_SLOPE * t0;
            float w0 = __expf(t0);
            dacc += w0;
            u = pack_sw(s, w0);
        }
        int cnt = min(row1 - base, 64);
        int iters = (cnt + 7) >> 3;
        int it = 0;
        for (; it + 1 < iters; it += 2) {
            int idxA = ((it << 3) + g) << 2;
            int idxB = (((it + 1) << 3) + g) << 2;
            uint uA = (uint)__builtin_amdgcn_ds_bpermute(idxA, (int)u);
            uint uB = (uint)__builtin_amdgcn_ds_bpermute(idxB, (int)u);
            uint2 UA = *(const uint2*)(featb + (size_t)sw_src(uA) * 32 + li * 4);
            uint2 UB = *(const uint2*)(featb + (size_t)sw_src(uB) * 32 + li * 4);
            float wA = sw_w(uA), wB = sw_w(uB);
            acc2[0] = unpack2(UA.x) * wA + acc2[0];
            acc2[1] = unpack2(UA.y) * wA + acc2[1];
            acc2[0] = unpack2(UB.x) * wB + acc2[0];
            acc2[1] = unpack2(UB.y) * wB + acc2[1];
        }
        if (it < iters) {
            int idx = ((it << 3) + g) << 2;
            uint uS = (uint)__builtin_amdgcn_ds_bpermute(idx, (int)u);
            uint2 U = *(const uint2*)(featb + (size_t)sw_src(uS) * 32 + li * 4);
            float wS = sw_w(uS);
            acc2[0] = unpack2(U.x) * wS + acc2[0];
            acc2[1] = unpack2(U.y) * wS + acc2[1];
        }
    }

#pragma unroll
    for (int r = 0; r < 2; ++r) {
        acc2[r].x += __shfl_xor(acc2[r].x, 8);
        acc2[r].y += __shfl_xor(acc2[r].y, 8);
        acc2[r].x += __shfl_xor(acc2[r].x, 16);
        acc2[r].y += __shfl_xor(acc2[r].y, 16);
        acc2[r].x += __shfl_xor(acc2[r].x, 32);
        acc2[r].y += __shfl_xor(acc2[r].y, 32);
    }
#pragma unroll
    for (int off = 1; off < 64; off <<= 1) dacc += __shfl_xor(dacc, off);

    if (lane < 8) {
        float inv = (row1 > row0) ? 1.f / dacc : 0.f;
        float4 b0 = ((const float4*)bias)[lane];
        float4 q;
        q.x = acc2[0].x * inv + b0.x;
        q.y = acc2[0].y * inv + b0.y;
        q.z = acc2[1].x * inv + b0.z;
        q.w = acc2[1].y * inv + b0.w;
        ((float4*)(out + (size_t)node * 32))[lane] = q;
    }
}

// ---------------- host ----------------

extern "C" void kernel_launch(void* const* d_in, const int* in_sizes, int n_in,
                              void* d_out, int out_size, void* d_ws, size_t ws_size,
                              hipStream_t stream) {
    const float* features = (const float*)d_in[0];
    const int* esrc = (const int*)d_in[1];
    const int* edst = (const int*)d_in[2];
    const float* W1 = (const float*)d_in[3];
    const float* a1s = (const float*)d_in[4];
    const float* a1d = (const float*)d_in[5];
    const float* b1 = (const float*)d_in[6];
    const float* W2 = (const float*)d_in[7];
    const float* a2s = (const float*)d_in[8];
    const float* a2d = (const float*)d_in[9];
    const float* b2 = (const float*)d_in[10];
    const float* W3 = (const float*)d_in[11];
    const float* a3s = (const float*)d_in[12];
    const float* a3d = (const float*)d_in[13];
    const float* b3 = (const float*)d_in[14];

    int N = in_sizes[0] / 128;
    int E = in_sizes[1];
    int nb = (N + SCAN_CH - 1) / SCAN_CH;

    char* base = (char*)d_ws;
    size_t off = 0;
    auto nxt = [&](size_t bytes) {
        void* p = base + off;
        off += (bytes + 255) & ~(size_t)255;
        return p;
    };
    ushort* Xb = (ushort*)nxt((size_t)N * 128 * 2);   // bf16 features (layer-1 input)
    ushort* Yb = (ushort*)nxt((size_t)N * 128 * 2);   // gemm out / agg4 in
    ushort* Bb = (ushort*)nxt((size_t)N * 128 * 2);   // agg4 out / gemm in
    ushort* Y3b = (ushort*)nxt((size_t)N * 32 * 2);   // gemm32 out
    float* el = (float*)nxt((size_t)N * 4 * 4);
    float* er = (float*)nxt((size_t)N * 4 * 4);
    int* deg = (int*)nxt((size_t)N * 4);
    int* rowptr = (int*)nxt((size_t)(N + 1) * 4);
    int* csrc = (int*)nxt((size_t)E * 4);
    int* rank = (int*)nxt((size_t)E * 4);
    int* bsum = (int*)nxt((size_t)(nb + 1) * 4);
    int* boff = (int*)nxt((size_t)(nb + 1) * 4);
    ushort* wf1 = (ushort*)nxt(16384 * 2);
    ushort* wf2 = (ushort*)nxt(16384 * 2);
    ushort* wf3 = (ushort*)nxt(4096 * 2);

    int gemm_grid = (N + 63) / 64;

    // CSR build + input conversions
    zero_ints<<<(N + 255) / 256, 256, 0, stream>>>(deg, N);
    hist_kernel<<<(E + 255) / 256, 256, 0, stream>>>(edst, deg, rank, E);
    cvt_bf16_kernel<<<(N * 16 + 255) / 256, 256, 0, stream>>>(features, Xb, N * 16);
    wpack_kernel<128><<<8, 256, 0, stream>>>(W1, wf1);
    wpack_kernel<128><<<8, 256, 0, stream>>>(W2, wf2);
    wpack_kernel<32><<<2, 256, 0, stream>>>(W3, wf3);
    scan_blocksum<<<nb, 256, 0, stream>>>(deg, bsum, N);
    scan_bsum<<<1, 64, 0, stream>>>(bsum, boff, nb);
    scan_write<<<nb, 256, 0, stream>>>(deg, boff, rowptr, N);
    fill_kernel<<<(E + 255) / 256, 256, 0, stream>>>(esrc, edst, rowptr, rank, csrc, E);

    // layer 1: 128 -> 4x32, ELU
    gemm_mfma_kernel<128><<<gemm_grid, 256, 0, stream>>>(Xb, wf1, Yb, a1s, a1d, el, er, N);
    agg4_kernel<true><<<(N + 3) / 4, 256, 0, stream>>>(Yb, el, er, rowptr, csrc, b1, Bb, N);

    // layer 2: 128 -> 4x32, ELU
    gemm_mfma_kernel<128><<<gemm_grid, 256, 0, stream>>>(Bb, wf2, Yb, a2s, a2d, el, er, N);
    agg4_kernel<true><<<(N + 3) / 4, 256, 0, stream>>>(Yb, el, er, rowptr, csrc, b2, Bb, N);

    // layer 3: 128 -> 1x32, no ELU, mean over 1 head = identity
    gemm_mfma_kernel<32><<<gemm_grid, 256, 0, stream>>>(Bb, wf3, Y3b, a3s, a3d, el, er, N);
    agg1_kernel<<<(N + 3) / 4, 256, 0, stream>>>(Y3b, el, er, rowptr, csrc, b3,
                                                 (float*)d_out, N);
}

// Round 17
// 218.700 us; speedup vs baseline: 2.8655x; 1.0320x over previous
//
#include <hip/hip_runtime.h>
#include <hip/hip_fp16.h>

#define NEG_SLOPE 0.2f

typedef unsigned int uint;
typedef unsigned short ushort;
typedef __attribute__((ext_vector_type(8))) short bf16x8;
typedef __attribute__((ext_vector_type(4))) float f32x4;
typedef __attribute__((ext_vector_type(2))) float f32x2;

__device__ __forceinline__ uint pack_bf16x2(float a, float b) {
    uint ba = __float_as_uint(a);
    uint bb = __float_as_uint(b);
    uint ra = (ba + 0x7FFFu + ((ba >> 16) & 1u)) >> 16;
    uint rb = (bb + 0x7FFFu + ((bb >> 16) & 1u)) >> 16;
    return ra | (rb << 16);
}

__device__ __forceinline__ ushort bf16_rne(float v) {
    uint b = __float_as_uint(v);
    return (ushort)((b + 0x7FFFu + ((b >> 16) & 1u)) >> 16);
}

__device__ __forceinline__ f32x2 unpack2(uint u) {
    f32x2 r;
    r.x = __uint_as_float(u << 16);
    r.y = __uint_as_float(u & 0xFFFF0000u);
    return r;
}

__device__ __forceinline__ uint pack_sw(int s, float w) {
    return ((uint)s << 16) | (uint)__half_as_ushort(__float2half_rn(w));
}

__device__ __forceinline__ int sw_src(uint u) { return (int)(u >> 16); }
__device__ __forceinline__ float sw_w(uint u) {
    return __half2float(__ushort_as_half((ushort)(u & 0xFFFFu)));
}

// ---------------- CSR build ----------------

__global__ void hist_kernel(const int* __restrict__ dst, int* __restrict__ deg,
                            int* __restrict__ rank, int E) {
    int i = blockIdx.x * 256 + threadIdx.x;
    if (i < E) rank[i] = atomicAdd(&deg[dst[i]], 1);
}

#define SCAN_CH 2048

__global__ __launch_bounds__(256) void scan_blocksum(const int* __restrict__ deg,
                                                     int* __restrict__ bsum, int N) {
    int blk = blockIdx.x, t = threadIdx.x;
    int base = blk * SCAN_CH;
    int s = 0;
#pragma unroll
    for (int i = 0; i < SCAN_CH / 256; ++i) {
        int idx = base + t + i * 256;
        if (idx < N) s += deg[idx];
    }
#pragma unroll
    for (int off = 1; off < 64; off <<= 1) s += __shfl_xor(s, off);
    __shared__ int wt[4];
    if ((t & 63) == 0) wt[t >> 6] = s;
    __syncthreads();
    if (t == 0) bsum[blk] = wt[0] + wt[1] + wt[2] + wt[3];
}

__global__ void scan_bsum(const int* __restrict__ bsum, int* __restrict__ boff, int nb) {
    int t = threadIdx.x;
    int orig = (t < nb) ? bsum[t] : 0;
    int v = orig;
#pragma unroll
    for (int off = 1; off < 64; off <<= 1) {
        int u = __shfl_up(v, off);
        if (t >= off) v += u;
    }
    if (t < nb) boff[t] = v - orig;
}

__global__ __launch_bounds__(256) void scan_write(const int* __restrict__ deg,
                                                  const int* __restrict__ boff,
                                                  int* __restrict__ rowptr, int N) {
    int blk = blockIdx.x, t = threadIdx.x;
    int base = blk * SCAN_CH + t * 8;
    int v[8];
    int s = 0;
#pragma unroll
    for (int r = 0; r < 8; ++r) {
        int idx = base + r;
        v[r] = (idx < N) ? deg[idx] : 0;
        s += v[r];
    }
    int lane = t & 63, wid = t >> 6;
    int p = s;
#pragma unroll
    for (int off = 1; off < 64; off <<= 1) {
        int u = __shfl_up(p, off);
        if (lane >= off) p += u;
    }
    __shared__ int wtot[4];
    if (lane == 63) wtot[wid] = p;
    __syncthreads();
    int run = boff[blk];
    for (int w = 0; w < wid; ++w) run += wtot[w];
    run += p - s;
#pragma unroll
    for (int r = 0; r < 8; ++r) {
        int idx = base + r;
        if (idx < N) {
            rowptr[idx] = run;
            run += v[r];
            if (idx == N - 1) rowptr[N] = run;
        }
    }
}

__global__ void fill_kernel(const int* __restrict__ src, const int* __restrict__ dst,
                            const int* __restrict__ rowptr, const int* __restrict__ rank,
                            int* __restrict__ csrc, int E) {
    int i = blockIdx.x * 256 + threadIdx.x;
    if (i < E) {
        int d = dst[i];
        __builtin_nontemporal_store(src[i], csrc + rowptr[d] + rank[i]);
    }
}

// -------- fused prep: fp32->bf16 cvt + 3x W-fragment pack --------
// frag[ct][kt][lane][j] = W[kt*32 + (lane>>4)*8 + j][ct*16 + (lane&15)]

template <int OUTF>
__device__ __forceinline__ void wpack_body(const float* __restrict__ W,
                                           ushort* __restrict__ wfrag, int idx) {
    constexpr int TOT = (OUTF / 16) * 4 * 64;
    if (idx >= TOT) return;
    int lane = idx & 63;
    int kt = (idx >> 6) & 3;
    int ct = idx >> 8;
    int col = ct * 16 + (lane & 15);
    int k0 = kt * 32 + (lane >> 4) * 8;
    uint4 q;
    q.x = pack_bf16x2(W[(k0 + 0) * OUTF + col], W[(k0 + 1) * OUTF + col]);
    q.y = pack_bf16x2(W[(k0 + 2) * OUTF + col], W[(k0 + 3) * OUTF + col]);
    q.z = pack_bf16x2(W[(k0 + 4) * OUTF + col], W[(k0 + 5) * OUTF + col]);
    q.w = pack_bf16x2(W[(k0 + 6) * OUTF + col], W[(k0 + 7) * OUTF + col]);
    ((uint4*)wfrag)[idx] = q;
}

__global__ __launch_bounds__(256) void prep_kernel(const float* __restrict__ X,
                                                   ushort* __restrict__ Xb, int n8,
                                                   int cvtblocks,
                                                   const float* __restrict__ W1,
                                                   ushort* __restrict__ wf1,
                                                   const float* __restrict__ W2,
                                                   ushort* __restrict__ wf2,
                                                   const float* __restrict__ W3,
                                                   ushort* __restrict__ wf3) {
    int b = blockIdx.x;
    int t = threadIdx.x;
    if (b < cvtblocks) {
        int i = b * 256 + t;
        if (i >= n8) return;
        const float4* xp = (const float4*)X + (size_t)i * 2;
        float4 v0 = xp[0], v1 = xp[1];
        uint4 q;
        q.x = pack_bf16x2(v0.x, v0.y);
        q.y = pack_bf16x2(v0.z, v0.w);
        q.z = pack_bf16x2(v1.x, v1.y);
        q.w = pack_bf16x2(v1.z, v1.w);
        ((uint4*)Xb)[i] = q;
    } else if (b < cvtblocks + 8) {
        wpack_body<128>(W1, wf1, (b - cvtblocks) * 256 + t);
    } else if (b < cvtblocks + 16) {
        wpack_body<128>(W2, wf2, (b - cvtblocks - 8) * 256 + t);
    } else {
        wpack_body<32>(W3, wf3, (b - cvtblocks - 16) * 256 + t);
    }
}

// -------- MFMA GEMM: Yb[N,OUTF] (bf16) = Xb[N,128] @ W + fused el/er --------

template <int OUTF>
__global__ __launch_bounds__(256) void gemm_mfma_kernel(const ushort* __restrict__ Xb,
                                                        const ushort* __restrict__ wfrag,
                                                        ushort* __restrict__ Yb,
                                                        const float* __restrict__ as_,
                                                        const float* __restrict__ ad_,
                                                        float* __restrict__ el,
                                                        float* __restrict__ er, int N) {
    constexpr int H = OUTF / 32;
    constexpr int NCT = OUTF / 16;
    int lane = threadIdx.x & 63;
    int wv = threadIdx.x >> 6;
    int r0 = blockIdx.x * 64 + wv * 16;
    if (r0 >= N) return;
    int lrow = lane & 15;
    int lk8 = lane >> 4;

    bf16x8 afrag[4];
    {
        int arow = min(r0 + lrow, N - 1);
        const ushort* xr = Xb + (size_t)arow * 128;
#pragma unroll
        for (int kt = 0; kt < 4; ++kt)
            afrag[kt] = *(const bf16x8*)(xr + kt * 32 + lk8 * 8);
    }

    float pel[H][4];
    float prr[H][4];
#pragma unroll
    for (int h = 0; h < H; ++h)
#pragma unroll
        for (int j = 0; j < 4; ++j) { pel[h][j] = 0.f; prr[h][j] = 0.f; }

    const bf16x8* wf = (const bf16x8*)wfrag;
#pragma unroll
    for (int ct = 0; ct < NCT; ++ct) {
        f32x4 acc = {0.f, 0.f, 0.f, 0.f};
#pragma unroll
        for (int kt = 0; kt < 4; ++kt) {
            bf16x8 b = wf[(ct * 4 + kt) * 64 + lane];
            acc = __builtin_amdgcn_mfma_f32_16x16x32_bf16(afrag[kt], b, acc, 0, 0, 0);
        }
        int col = ct * 16 + lrow;
        int h = (H == 1) ? 0 : (ct >> 1);
        float asc = as_[col], adc = ad_[col];
#pragma unroll
        for (int j = 0; j < 4; ++j) {
            int row = r0 + lk8 * 4 + j;
            float v = acc[j];
            if (row < N) Yb[(size_t)row * OUTF + col] = bf16_rne(v);
            pel[h][j] = fmaf(v, asc, pel[h][j]);
            prr[h][j] = fmaf(v, adc, prr[h][j]);
        }
    }

#pragma unroll
    for (int h = 0; h < H; ++h)
#pragma unroll
        for (int j = 0; j < 4; ++j) {
            float pe = pel[h][j], pr = prr[h][j];
#pragma unroll
            for (int off = 1; off < 16; off <<= 1) {
                pe += __shfl_xor(pe, off);
                pr += __shfl_xor(pr, off);
            }
            if (lrow == 0) {
                int row = r0 + lk8 * 4 + j;
                if (row < N) {
                    el[row * H + h] = pe;
                    er[row * H + h] = pr;
                }
            }
        }
}

// ---------------- aggregation (H=4, bf16 feat -> bf16 out) ----------------
// 1-deep software pipeline: next batch's csrc + el gathers issue before the
// current batch's bpermute/gather/fma block.

template <bool DOELU>
__global__ __launch_bounds__(256) void agg4_kernel(const ushort* __restrict__ featb,
                                                   const float* __restrict__ el,
                                                   const float* __restrict__ er,
                                                   const int* __restrict__ rowptr,
                                                   const int* __restrict__ csrc,
                                                   const float* __restrict__ bias,
                                                   ushort* __restrict__ outb, int N) {
    int lane = threadIdx.x & 63;
    int node = blockIdx.x * 4 + (threadIdx.x >> 6);
    if (node >= N) return;
    int row0 = __builtin_amdgcn_readfirstlane(rowptr[node]);
    int row1 = __builtin_amdgcn_readfirstlane(rowptr[node + 1]);

    int qe = lane >> 2;
    int qh = lane & 3;
    float ern = er[node * 4 + qh];

    int g = lane >> 4;
    int li = lane & 15;
    int h = li >> 2;
    int ib = (g << 4) + (h << 2);

    float dacc = 0.f;
    f32x2 acc2[4];
#pragma unroll
    for (int r = 0; r < 4; ++r) acc2[r] = (f32x2){0.f, 0.f};

    // pipeline prologue: batch 0 loads
    int e0 = row0 + qe;
    bool v = e0 < row1;
    int s = v ? csrc[e0] : 0;
    float elv = v ? el[s * 4 + qh] : 0.f;

    for (int base = row0; base < row1; base += 16) {
        uint u = 0;
        if (v) {
            float tt = elv + ern;
            tt = tt > 0.f ? tt : NEG_SLOPE * tt;
            float w = __expf(tt);
            dacc += w;
            u = pack_sw(s, w);
        }
        // prefetch next batch (loads in flight during gather/fma below)
        int en = base + 16 + qe;
        bool vn = en < row1;
        int sn = vn ? csrc[en] : 0;
        float elvn = vn ? el[sn * 4 + qh] : 0.f;

        uint u0 = (uint)__builtin_amdgcn_ds_bpermute(ib, (int)u);
        uint u1 = (uint)__builtin_amdgcn_ds_bpermute(ib + 64, (int)u);
        uint u2 = (uint)__builtin_amdgcn_ds_bpermute(ib + 128, (int)u);
        uint u3 = (uint)__builtin_amdgcn_ds_bpermute(ib + 192, (int)u);
        uint4 U0 = *(const uint4*)(featb + (size_t)sw_src(u0) * 128 + li * 8);
        uint4 U1 = *(const uint4*)(featb + (size_t)sw_src(u1) * 128 + li * 8);
        uint4 U2 = *(const uint4*)(featb + (size_t)sw_src(u2) * 128 + li * 8);
        uint4 U3 = *(const uint4*)(featb + (size_t)sw_src(u3) * 128 + li * 8);
        float w0 = sw_w(u0), w1 = sw_w(u1), w2 = sw_w(u2), w3 = sw_w(u3);
        acc2[0] = unpack2(U0.x) * w0 + acc2[0];
        acc2[1] = unpack2(U0.y) * w0 + acc2[1];
        acc2[2] = unpack2(U0.z) * w0 + acc2[2];
        acc2[3] = unpack2(U0.w) * w0 + acc2[3];
        acc2[0] = unpack2(U1.x) * w1 + acc2[0];
        acc2[1] = unpack2(U1.y) * w1 + acc2[1];
        acc2[2] = unpack2(U1.z) * w1 + acc2[2];
        acc2[3] = unpack2(U1.w) * w1 + acc2[3];
        acc2[0] = unpack2(U2.x) * w2 + acc2[0];
        acc2[1] = unpack2(U2.y) * w2 + acc2[1];
        acc2[2] = unpack2(U2.z) * w2 + acc2[2];
        acc2[3] = unpack2(U2.w) * w2 + acc2[3];
        acc2[0] = unpack2(U3.x) * w3 + acc2[0];
        acc2[1] = unpack2(U3.y) * w3 + acc2[1];
        acc2[2] = unpack2(U3.z) * w3 + acc2[2];
        acc2[3] = unpack2(U3.w) * w3 + acc2[3];

        v = vn; s = sn; elv = elvn;
    }

#pragma unroll
    for (int r = 0; r < 4; ++r) {
        acc2[r].x += __shfl_xor(acc2[r].x, 16);
        acc2[r].y += __shfl_xor(acc2[r].y, 16);
        acc2[r].x += __shfl_xor(acc2[r].x, 32);
        acc2[r].y += __shfl_xor(acc2[r].y, 32);
    }
#pragma unroll
    for (int off = 4; off < 64; off <<= 1) dacc += __shfl_xor(dacc, off);
    float d = __int_as_float(
        __builtin_amdgcn_ds_bpermute((li >> 2) << 2, __float_as_int(dacc)));

    if (lane < 16) {
        float inv = (row1 > row0) ? 1.f / d : 0.f;
        const float4* bv = (const float4*)bias + li * 2;
        float4 b0 = bv[0], b1 = bv[1];
        float o[8];
        o[0] = acc2[0].x * inv + b0.x;
        o[1] = acc2[0].y * inv + b0.y;
        o[2] = acc2[1].x * inv + b0.z;
        o[3] = acc2[1].y * inv + b0.w;
        o[4] = acc2[2].x * inv + b1.x;
        o[5] = acc2[2].y * inv + b1.y;
        o[6] = acc2[3].x * inv + b1.z;
        o[7] = acc2[3].y * inv + b1.w;
        if (DOELU) {
#pragma unroll
            for (int r = 0; r < 8; ++r) o[r] = o[r] > 0.f ? o[r] : __expf(o[r]) - 1.f;
        }
        uint4 q;
        q.x = pack_bf16x2(o[0], o[1]);
        q.y = pack_bf16x2(o[2], o[3]);
        q.z = pack_bf16x2(o[4], o[5]);
        q.w = pack_bf16x2(o[6], o[7]);
        *(uint4*)(outb + (size_t)node * 128 + li * 8) = q;
    }
}

// ---------------- aggregation (H=1, bf16 feat -> fp32 out) ----------------

__global__ __launch_bounds__(256) void agg1_kernel(const ushort* __restrict__ featb,
                                                   const float* __restrict__ el,
                                                   const float* __restrict__ er,
                                                   const int* __restrict__ rowptr,
                                                   const int* __restrict__ csrc,
                                                   const float* __restrict__ bias,
                                                   float* __restrict__ out, int N) {
    int lane = threadIdx.x & 63;
    int node = blockIdx.x * 4 + (threadIdx.x >> 6);
    if (node >= N) return;
    int row0 = __builtin_amdgcn_readfirstlane(rowptr[node]);
    int row1 = __builtin_amdgcn_readfirstlane(rowptr[node + 1]);

    float ern = er[node];
    int g = lane >> 3;
    int li = lane & 7;

    float dacc = 0.f;
    f32x2 acc2[2];
    acc2[0] = (f32x2){0.f, 0.f};
    acc2[1] = (f32x2){0.f, 0.f};

    for (int base = row0; base < row1; base += 64) {
        int e = base + lane;
        uint u = 0;
        if (e < row1) {
            int s = csrc[e];
            float t0 = el[s] + ern;
            t0 = t0 > 0.f ? t0 : NEG_SLOPE * t0;
            float w0 = __expf(t0);
            dacc += w0;
            u = pack_sw(s, w0);
        }
        int cnt = min(row1 - base, 64);
        int iters = (cnt + 7) >> 3;
        int it = 0;
        for (; it + 1 < iters; it += 2) {
            int idxA = ((it << 3) + g) << 2;
            int idxB = (((it + 1) << 3) + g) << 2;
            uint uA = (uint)__builtin_amdgcn_ds_bpermute(idxA, (int)u);
            uint uB = (uint)__builtin_amdgcn_ds_bpermute(idxB, (int)u);
            uint2 UA = *(const uint2*)(featb + (size_t)sw_src(uA) * 32 + li * 4);
            uint2 UB = *(const uint2*)(featb + (size_t)sw_src(uB) * 32 + li * 4);
            float wA = sw_w(uA), wB = sw_w(uB);
            acc2[0] = unpack2(UA.x) * wA + acc2[0];
            acc2[1] = unpack2(UA.y) * wA + acc2[1];
            acc2[0] = unpack2(UB.x) * wB + acc2[0];
            acc2[1] = unpack2(UB.y) * wB + acc2[1];
        }
        if (it < iters) {
            int idx = ((it << 3) + g) << 2;
            uint uS = (uint)__builtin_amdgcn_ds_bpermute(idx, (int)u);
            uint2 U = *(const uint2*)(featb + (size_t)sw_src(uS) * 32 + li * 4);
            float wS = sw_w(uS);
            acc2[0] = unpack2(U.x) * wS + acc2[0];
            acc2[1] = unpack2(U.y) * wS + acc2[1];
        }
    }

#pragma unroll
    for (int r = 0; r < 2; ++r) {
        acc2[r].x += __shfl_xor(acc2[r].x, 8);
        acc2[r].y += __shfl_xor(acc2[r].y, 8);
        acc2[r].x += __shfl_xor(acc2[r].x, 16);
        acc2[r].y += __shfl_xor(acc2[r].y, 16);
        acc2[r].x += __shfl_xor(acc2[r].x, 32);
        acc2[r].y += __shfl_xor(acc2[r].y, 32);
    }
#pragma unroll
    for (int off = 1; off < 64; off <<= 1) dacc += __shfl_xor(dacc, off);

    if (lane < 8) {
        float inv = (row1 > row0) ? 1.f / dacc : 0.f;
        float4 b0 = ((const float4*)bias)[lane];
        float4 q;
        q.x = acc2[0].x * inv + b0.x;
        q.y = acc2[0].y * inv + b0.y;
        q.z = acc2[1].x * inv + b0.z;
        q.w = acc2[1].y * inv + b0.w;
        ((float4*)(out + (size_t)node * 32))[lane] = q;
    }
}

// ---------------- host ----------------

extern "C" void kernel_launch(void* const* d_in, const int* in_sizes, int n_in,
                              void* d_out, int out_size, void* d_ws, size_t ws_size,
                              hipStream_t stream) {
    const float* features = (const float*)d_in[0];
    const int* esrc = (const int*)d_in[1];
    const int* edst = (const int*)d_in[2];
    const float* W1 = (const float*)d_in[3];
    const float* a1s = (const float*)d_in[4];
    const float* a1d = (const float*)d_in[5];
    const float* b1 = (const float*)d_in[6];
    const float* W2 = (const float*)d_in[7];
    const float* a2s = (const float*)d_in[8];
    const float* a2d = (const float*)d_in[9];
    const float* b2 = (const float*)d_in[10];
    const float* W3 = (const float*)d_in[11];
    const float* a3s = (const float*)d_in[12];
    const float* a3d = (const float*)d_in[13];
    const float* b3 = (const float*)d_in[14];

    int N = in_sizes[0] / 128;
    int E = in_sizes[1];
    int nb = (N + SCAN_CH - 1) / SCAN_CH;

    char* base = (char*)d_ws;
    size_t off = 0;
    auto nxt = [&](size_t bytes) {
        void* p = base + off;
        off += (bytes + 255) & ~(size_t)255;
        return p;
    };
    ushort* Xb = (ushort*)nxt((size_t)N * 128 * 2);   // bf16 features (layer-1 input)
    ushort* Yb = (ushort*)nxt((size_t)N * 128 * 2);   // gemm out / agg4 in
    ushort* Bb = (ushort*)nxt((size_t)N * 128 * 2);   // agg4 out / gemm in
    ushort* Y3b = (ushort*)nxt((size_t)N * 32 * 2);   // gemm32 out
    float* el = (float*)nxt((size_t)N * 4 * 4);
    float* er = (float*)nxt((size_t)N * 4 * 4);
    int* deg = (int*)nxt((size_t)N * 4);
    int* rowptr = (int*)nxt((size_t)(N + 1) * 4);
    int* csrc = (int*)nxt((size_t)E * 4);
    int* rank = (int*)nxt((size_t)E * 4);
    int* bsum = (int*)nxt((size_t)(nb + 1) * 4);
    int* boff = (int*)nxt((size_t)(nb + 1) * 4);
    ushort* wf1 = (ushort*)nxt(16384 * 2);
    ushort* wf2 = (ushort*)nxt(16384 * 2);
    ushort* wf3 = (ushort*)nxt(4096 * 2);

    int gemm_grid = (N + 63) / 64;
    int n8 = N * 16;
    int cvtblocks = (n8 + 255) / 256;

    // CSR build + input conversions
    hipMemsetAsync(deg, 0, (size_t)N * 4, stream);
    hist_kernel<<<(E + 255) / 256, 256, 0, stream>>>(edst, deg, rank, E);
    prep_kernel<<<cvtblocks + 18, 256, 0, stream>>>(features, Xb, n8, cvtblocks,
                                                    W1, wf1, W2, wf2, W3, wf3);
    scan_blocksum<<<nb, 256, 0, stream>>>(deg, bsum, N);
    scan_bsum<<<1, 64, 0, stream>>>(bsum, boff, nb);
    scan_write<<<nb, 256, 0, stream>>>(deg, boff, rowptr, N);
    fill_kernel<<<(E + 255) / 256, 256, 0, stream>>>(esrc, edst, rowptr, rank, csrc, E);

    // layer 1: 128 -> 4x32, ELU
    gemm_mfma_kernel<128><<<gemm_grid, 256, 0, stream>>>(Xb, wf1, Yb, a1s, a1d, el, er, N);
    agg4_kernel<true><<<(N + 3) / 4, 256, 0, stream>>>(Yb, el, er, rowptr, csrc, b1, Bb, N);

    // layer 2: 128 -> 4x32, ELU
    gemm_mfma_kernel<128><<<gemm_grid, 256, 0, stream>>>(Bb, wf2, Yb, a2s, a2d, el, er, N);
    agg4_kernel<true><<<(N + 3) / 4, 256, 0, stream>>>(Yb, el, er, rowptr, csrc, b2, Bb, N);

    // layer 3: 128 -> 1x32, no ELU, mean over 1 head = identity
    gemm_mfma_kernel<32><<<gemm_grid, 256, 0, stream>>>(Bb, wf3, Y3b, a3s, a3d, el, er, N);
    agg1_kernel<<<(N + 3) / 4, 256, 0, stream>>>(Y3b, el, er, rowptr, csrc, b3,
                                                 (float*)d_out, N);
}

// Round 18
// 218.512 us; speedup vs baseline: 2.8680x; 1.0009x over previous
//
#include <hip/hip_runtime.h>
#include <hip/hip_fp16.h>

#define NEG_SLOPE 0.2f

typedef unsigned int uint;
typedef unsigned short ushort;
typedef __attribute__((ext_vector_type(8))) short bf16x8;
typedef __attribute__((ext_vector_type(4))) float f32x4;
typedef __attribute__((ext_vector_type(2))) float f32x2;

__device__ __forceinline__ uint pack_bf16x2(float a, float b) {
    uint ba = __float_as_uint(a);
    uint bb = __float_as_uint(b);
    uint ra = (ba + 0x7FFFu + ((ba >> 16) & 1u)) >> 16;
    uint rb = (bb + 0x7FFFu + ((bb >> 16) & 1u)) >> 16;
    return ra | (rb << 16);
}

__device__ __forceinline__ ushort bf16_rne(float v) {
    uint b = __float_as_uint(v);
    return (ushort)((b + 0x7FFFu + ((b >> 16) & 1u)) >> 16);
}

__device__ __forceinline__ f32x2 unpack2(uint u) {
    f32x2 r;
    r.x = __uint_as_float(u << 16);
    r.y = __uint_as_float(u & 0xFFFF0000u);
    return r;
}

__device__ __forceinline__ uint pack_sw(int s, float w) {
    return ((uint)s << 16) | (uint)__half_as_ushort(__float2half_rn(w));
}

__device__ __forceinline__ int sw_src(uint u) { return (int)(u >> 16); }
__device__ __forceinline__ float sw_w(uint u) {
    return __half2float(__ushort_as_half((ushort)(u & 0xFFFFu)));
}

// ---------------- CSR build (8-way sharded histogram) ----------------
// Shard c = blockIdx&7: round-robin block->XCD dispatch keeps each shard's
// counter lines in (mostly) one XCD's L2 -> no cross-XCD line ping-pong.

__global__ void hist_kernel(const int* __restrict__ dst, int* __restrict__ deg8,
                            int* __restrict__ rank, int E, int N) {
    int i = blockIdx.x * 256 + threadIdx.x;
    if (i < E) {
        int c = blockIdx.x & 7;
        rank[i] = atomicAdd(&deg8[c * N + dst[i]], 1);
    }
}

// per-node prefix over the 8 shards (in place: deg8 -> shard base), total -> deg
__global__ __launch_bounds__(256) void base8_kernel(int* __restrict__ deg8,
                                                    int* __restrict__ deg, int N) {
    int i = blockIdx.x * 256 + threadIdx.x;
    if (i >= N) return;
    int run = 0;
#pragma unroll
    for (int c = 0; c < 8; ++c) {
        int v = deg8[c * N + i];
        deg8[c * N + i] = run;
        run += v;
    }
    deg[i] = run;
}

#define SCAN_CH 2048

__global__ __launch_bounds__(256) void scan_blocksum(const int* __restrict__ deg,
                                                     int* __restrict__ bsum, int N) {
    int blk = blockIdx.x, t = threadIdx.x;
    int base = blk * SCAN_CH;
    int s = 0;
#pragma unroll
    for (int i = 0; i < SCAN_CH / 256; ++i) {
        int idx = base + t + i * 256;
        if (idx < N) s += deg[idx];
    }
#pragma unroll
    for (int off = 1; off < 64; off <<= 1) s += __shfl_xor(s, off);
    __shared__ int wt[4];
    if ((t & 63) == 0) wt[t >> 6] = s;
    __syncthreads();
    if (t == 0) bsum[blk] = wt[0] + wt[1] + wt[2] + wt[3];
}

__global__ void scan_bsum(const int* __restrict__ bsum, int* __restrict__ boff, int nb) {
    int t = threadIdx.x;
    int orig = (t < nb) ? bsum[t] : 0;
    int v = orig;
#pragma unroll
    for (int off = 1; off < 64; off <<= 1) {
        int u = __shfl_up(v, off);
        if (t >= off) v += u;
    }
    if (t < nb) boff[t] = v - orig;
}

__global__ __launch_bounds__(256) void scan_write(const int* __restrict__ deg,
                                                  const int* __restrict__ boff,
                                                  int* __restrict__ rowptr, int N) {
    int blk = blockIdx.x, t = threadIdx.x;
    int base = blk * SCAN_CH + t * 8;
    int v[8];
    int s = 0;
#pragma unroll
    for (int r = 0; r < 8; ++r) {
        int idx = base + r;
        v[r] = (idx < N) ? deg[idx] : 0;
        s += v[r];
    }
    int lane = t & 63, wid = t >> 6;
    int p = s;
#pragma unroll
    for (int off = 1; off < 64; off <<= 1) {
        int u = __shfl_up(p, off);
        if (lane >= off) p += u;
    }
    __shared__ int wtot[4];
    if (lane == 63) wtot[wid] = p;
    __syncthreads();
    int run = boff[blk];
    for (int w = 0; w < wid; ++w) run += wtot[w];
    run += p - s;
#pragma unroll
    for (int r = 0; r < 8; ++r) {
        int idx = base + r;
        if (idx < N) {
            rowptr[idx] = run;
            run += v[r];
            if (idx == N - 1) rowptr[N] = run;
        }
    }
}

// scatter: pos = rowptr[d] + shard_base[c][d] + within-shard rank
// c recomputed with the same global-thread formula as hist_kernel.
__global__ void fill_kernel(const int* __restrict__ src, const int* __restrict__ dst,
                            const int* __restrict__ rowptr, const int* __restrict__ rank,
                            const int* __restrict__ base8,
                            int* __restrict__ csrc, int E, int N) {
    int i = blockIdx.x * 256 + threadIdx.x;
    if (i < E) {
        int c = blockIdx.x & 7;
        int d = dst[i];
        __builtin_nontemporal_store(src[i],
                                    csrc + rowptr[d] + base8[c * N + d] + rank[i]);
    }
}

// -------- fused prep: fp32->bf16 cvt + 3x W-fragment pack --------
// frag[ct][kt][lane][j] = W[kt*32 + (lane>>4)*8 + j][ct*16 + (lane&15)]

template <int OUTF>
__device__ __forceinline__ void wpack_body(const float* __restrict__ W,
                                           ushort* __restrict__ wfrag, int idx) {
    constexpr int TOT = (OUTF / 16) * 4 * 64;
    if (idx >= TOT) return;
    int lane = idx & 63;
    int kt = (idx >> 6) & 3;
    int ct = idx >> 8;
    int col = ct * 16 + (lane & 15);
    int k0 = kt * 32 + (lane >> 4) * 8;
    uint4 q;
    q.x = pack_bf16x2(W[(k0 + 0) * OUTF + col], W[(k0 + 1) * OUTF + col]);
    q.y = pack_bf16x2(W[(k0 + 2) * OUTF + col], W[(k0 + 3) * OUTF + col]);
    q.z = pack_bf16x2(W[(k0 + 4) * OUTF + col], W[(k0 + 5) * OUTF + col]);
    q.w = pack_bf16x2(W[(k0 + 6) * OUTF + col], W[(k0 + 7) * OUTF + col]);
    ((uint4*)wfrag)[idx] = q;
}

__global__ __launch_bounds__(256) void prep_kernel(const float* __restrict__ X,
                                                   ushort* __restrict__ Xb, int n8,
                                                   int cvtblocks,
                                                   const float* __restrict__ W1,
                                                   ushort* __restrict__ wf1,
                                                   const float* __restrict__ W2,
                                                   ushort* __restrict__ wf2,
                                                   const float* __restrict__ W3,
                                                   ushort* __restrict__ wf3) {
    int b = blockIdx.x;
    int t = threadIdx.x;
    if (b < cvtblocks) {
        int i = b * 256 + t;
        if (i >= n8) return;
        const float4* xp = (const float4*)X + (size_t)i * 2;
        float4 v0 = xp[0], v1 = xp[1];
        uint4 q;
        q.x = pack_bf16x2(v0.x, v0.y);
        q.y = pack_bf16x2(v0.z, v0.w);
        q.z = pack_bf16x2(v1.x, v1.y);
        q.w = pack_bf16x2(v1.z, v1.w);
        ((uint4*)Xb)[i] = q;
    } else if (b < cvtblocks + 8) {
        wpack_body<128>(W1, wf1, (b - cvtblocks) * 256 + t);
    } else if (b < cvtblocks + 16) {
        wpack_body<128>(W2, wf2, (b - cvtblocks - 8) * 256 + t);
    } else {
        wpack_body<32>(W3, wf3, (b - cvtblocks - 16) * 256 + t);
    }
}

// -------- MFMA GEMM: Yb[N,OUTF] (bf16) = Xb[N,128] @ W + fused el/er --------

template <int OUTF>
__global__ __launch_bounds__(256) void gemm_mfma_kernel(const ushort* __restrict__ Xb,
                                                        const ushort* __restrict__ wfrag,
                                                        ushort* __restrict__ Yb,
                                                        const float* __restrict__ as_,
                                                        const float* __restrict__ ad_,
                                                        float* __restrict__ el,
                                                        float* __restrict__ er, int N) {
    constexpr int H = OUTF / 32;
    constexpr int NCT = OUTF / 16;
    int lane = threadIdx.x & 63;
    int wv = threadIdx.x >> 6;
    int r0 = blockIdx.x * 64 + wv * 16;
    if (r0 >= N) return;
    int lrow = lane & 15;
    int lk8 = lane >> 4;

    bf16x8 afrag[4];
    {
        int arow = min(r0 + lrow, N - 1);
        const ushort* xr = Xb + (size_t)arow * 128;
#pragma unroll
        for (int kt = 0; kt < 4; ++kt)
            afrag[kt] = *(const bf16x8*)(xr + kt * 32 + lk8 * 8);
    }

    float pel[H][4];
    float prr[H][4];
#pragma unroll
    for (int h = 0; h < H; ++h)
#pragma unroll
        for (int j = 0; j < 4; ++j) { pel[h][j] = 0.f; prr[h][j] = 0.f; }

    const bf16x8* wf = (const bf16x8*)wfrag;
#pragma unroll
    for (int ct = 0; ct < NCT; ++ct) {
        f32x4 acc = {0.f, 0.f, 0.f, 0.f};
#pragma unroll
        for (int kt = 0; kt < 4; ++kt) {
            bf16x8 b = wf[(ct * 4 + kt) * 64 + lane];
            acc = __builtin_amdgcn_mfma_f32_16x16x32_bf16(afrag[kt], b, acc, 0, 0, 0);
        }
        int col = ct * 16 + lrow;
        int h = (H == 1) ? 0 : (ct >> 1);
        float asc = as_[col], adc = ad_[col];
#pragma unroll
        for (int j = 0; j < 4; ++j) {
            int row = r0 + lk8 * 4 + j;
            float v = acc[j];
            if (row < N) Yb[(size_t)row * OUTF + col] = bf16_rne(v);
            pel[h][j] = fmaf(v, asc, pel[h][j]);
            prr[h][j] = fmaf(v, adc, prr[h][j]);
        }
    }

#pragma unroll
    for (int h = 0; h < H; ++h)
#pragma unroll
        for (int j = 0; j < 4; ++j) {
            float pe = pel[h][j], pr = prr[h][j];
#pragma unroll
            for (int off = 1; off < 16; off <<= 1) {
                pe += __shfl_xor(pe, off);
                pr += __shfl_xor(pr, off);
            }
            if (lrow == 0) {
                int row = r0 + lk8 * 4 + j;
                if (row < N) {
                    el[row * H + h] = pe;
                    er[row * H + h] = pr;
                }
            }
        }
}

// ---------------- aggregation (H=4, bf16 feat -> bf16 out) ----------------
// 1-deep software pipeline: next batch's csrc + el gathers issue before the
// current batch's bpermute/gather/fma block.

template <bool DOELU>
__global__ __launch_bounds__(256) void agg4_kernel(const ushort* __restrict__ featb,
                                                   const float* __restrict__ el,
                                                   const float* __restrict__ er,
                                                   const int* __restrict__ rowptr,
                                                   const int* __restrict__ csrc,
                                                   const float* __restrict__ bias,
                                                   ushort* __restrict__ outb, int N) {
    int lane = threadIdx.x & 63;
    int node = blockIdx.x * 4 + (threadIdx.x >> 6);
    if (node >= N) return;
    int row0 = __builtin_amdgcn_readfirstlane(rowptr[node]);
    int row1 = __builtin_amdgcn_readfirstlane(rowptr[node + 1]);

    int qe = lane >> 2;
    int qh = lane & 3;
    float ern = er[node * 4 + qh];

    int g = lane >> 4;
    int li = lane & 15;
    int h = li >> 2;
    int ib = (g << 4) + (h << 2);

    float dacc = 0.f;
    f32x2 acc2[4];
#pragma unroll
    for (int r = 0; r < 4; ++r) acc2[r] = (f32x2){0.f, 0.f};

    // pipeline prologue: batch 0 loads
    int e0 = row0 + qe;
    bool v = e0 < row1;
    int s = v ? csrc[e0] : 0;
    float elv = v ? el[s * 4 + qh] : 0.f;

    for (int base = row0; base < row1; base += 16) {
        uint u = 0;
        if (v) {
            float tt = elv + ern;
            tt = tt > 0.f ? tt : NEG_SLOPE * tt;
            float w = __expf(tt);
            dacc += w;
            u = pack_sw(s, w);
        }
        // prefetch next batch (loads in flight during gather/fma below)
        int en = base + 16 + qe;
        bool vn = en < row1;
        int sn = vn ? csrc[en] : 0;
        float elvn = vn ? el[sn * 4 + qh] : 0.f;

        uint u0 = (uint)__builtin_amdgcn_ds_bpermute(ib, (int)u);
        uint u1 = (uint)__builtin_amdgcn_ds_bpermute(ib + 64, (int)u);
        uint u2 = (uint)__builtin_amdgcn_ds_bpermute(ib + 128, (int)u);
        uint u3 = (uint)__builtin_amdgcn_ds_bpermute(ib + 192, (int)u);
        uint4 U0 = *(const uint4*)(featb + (size_t)sw_src(u0) * 128 + li * 8);
        uint4 U1 = *(const uint4*)(featb + (size_t)sw_src(u1) * 128 + li * 8);
        uint4 U2 = *(const uint4*)(featb + (size_t)sw_src(u2) * 128 + li * 8);
        uint4 U3 = *(const uint4*)(featb + (size_t)sw_src(u3) * 128 + li * 8);
        float w0 = sw_w(u0), w1 = sw_w(u1), w2 = sw_w(u2), w3 = sw_w(u3);
        acc2[0] = unpack2(U0.x) * w0 + acc2[0];
        acc2[1] = unpack2(U0.y) * w0 + acc2[1];
        acc2[2] = unpack2(U0.z) * w0 + acc2[2];
        acc2[3] = unpack2(U0.w) * w0 + acc2[3];
        acc2[0] = unpack2(U1.x) * w1 + acc2[0];
        acc2[1] = unpack2(U1.y) * w1 + acc2[1];
        acc2[2] = unpack2(U1.z) * w1 + acc2[2];
        acc2[3] = unpack2(U1.w) * w1 + acc2[3];
        acc2[0] = unpack2(U2.x) * w2 + acc2[0];
        acc2[1] = unpack2(U2.y) * w2 + acc2[1];
        acc2[2] = unpack2(U2.z) * w2 + acc2[2];
        acc2[3] = unpack2(U2.w) * w2 + acc2[3];
        acc2[0] = unpack2(U3.x) * w3 + acc2[0];
        acc2[1] = unpack2(U3.y) * w3 + acc2[1];
        acc2[2] = unpack2(U3.z) * w3 + acc2[2];
        acc2[3] = unpack2(U3.w) * w3 + acc2[3];

        v = vn; s = sn; elv = elvn;
    }

#pragma unroll
    for (int r = 0; r < 4; ++r) {
        acc2[r].x += __shfl_xor(acc2[r].x, 16);
        acc2[r].y += __shfl_xor(acc2[r].y, 16);
        acc2[r].x += __shfl_xor(acc2[r].x, 32);
        acc2[r].y += __shfl_xor(acc2[r].y, 32);
    }
#pragma unroll
    for (int off = 4; off < 64; off <<= 1) dacc += __shfl_xor(dacc, off);
    float d = __int_as_float(
        __builtin_amdgcn_ds_bpermute((li >> 2) << 2, __float_as_int(dacc)));

    if (lane < 16) {
        float inv = (row1 > row0) ? 1.f / d : 0.f;
        const float4* bv = (const float4*)bias + li * 2;
        float4 b0 = bv[0], b1 = bv[1];
        float o[8];
        o[0] = acc2[0].x * inv + b0.x;
        o[1] = acc2[0].y * inv + b0.y;
        o[2] = acc2[1].x * inv + b0.z;
        o[3] = acc2[1].y * inv + b0.w;
        o[4] = acc2[2].x * inv + b1.x;
        o[5] = acc2[2].y * inv + b1.y;
        o[6] = acc2[3].x * inv + b1.z;
        o[7] = acc2[3].y * inv + b1.w;
        if (DOELU) {
#pragma unroll
            for (int r = 0; r < 8; ++r) o[r] = o[r] > 0.f ? o[r] : __expf(o[r]) - 1.f;
        }
        uint4 q;
        q.x = pack_bf16x2(o[0], o[1]);
        q.y = pack_bf16x2(o[2], o[3]);
        q.z = pack_bf16x2(o[4], o[5]);
        q.w = pack_bf16x2(o[6], o[7]);
        *(uint4*)(outb + (size_t)node * 128 + li * 8) = q;
    }
}

// ---------------- aggregation (H=1, bf16 feat -> fp32 out) ----------------

__global__ __launch_bounds__(256) void agg1_kernel(const ushort* __restrict__ featb,
                                                   const float* __restrict__ el,
                                                   const float* __restrict__ er,
                                                   const int* __restrict__ rowptr,
                                                   const int* __restrict__ csrc,
                                                   const float* __restrict__ bias,
                                                   float* __restrict__ out, int N) {
    int lane = threadIdx.x & 63;
    int node = blockIdx.x * 4 + (threadIdx.x >> 6);
    if (node >= N) return;
    int row0 = __builtin_amdgcn_readfirstlane(rowptr[node]);
    int row1 = __builtin_amdgcn_readfirstlane(rowptr[node + 1]);

    float ern = er[node];
    int g = lane >> 3;
    int li = lane & 7;

    float dacc = 0.f;
    f32x2 acc2[2];
    acc2[0] = (f32x2){0.f, 0.f};
    acc2[1] = (f32x2){0.f, 0.f};

    for (int base = row0; base < row1; base += 64) {
        int e = base + lane;
        uint u = 0;
        if (e < row1) {
            int s = csrc[e];
            float t0 = el[s] + ern;
            t0 = t0 > 0.f ? t0 : NEG_SLOPE * t0;
            float w0 = __expf(t0);
            dacc += w0;
            u = pack_sw(s, w0);
        }
        int cnt = min(row1 - base, 64);
        int iters = (cnt + 7) >> 3;
        int it = 0;
        for (; it + 1 < iters; it += 2) {
            int idxA = ((it << 3) + g) << 2;
            int idxB = (((it + 1) << 3) + g) << 2;
            uint uA = (uint)__builtin_amdgcn_ds_bpermute(idxA, (int)u);
            uint uB = (uint)__builtin_amdgcn_ds_bpermute(idxB, (int)u);
            uint2 UA = *(const uint2*)(featb + (size_t)sw_src(uA) * 32 + li * 4);
            uint2 UB = *(const uint2*)(featb + (size_t)sw_src(uB) * 32 + li * 4);
            float wA = sw_w(uA), wB = sw_w(uB);
            acc2[0] = unpack2(UA.x) * wA + acc2[0];
            acc2[1] = unpack2(UA.y) * wA + acc2[1];
            acc2[0] = unpack2(UB.x) * wB + acc2[0];
            acc2[1] = unpack2(UB.y) * wB + acc2[1];
        }
        if (it < iters) {
            int idx = ((it << 3) + g) << 2;
            uint uS = (uint)__builtin_amdgcn_ds_bpermute(idx, (int)u);
            uint2 U = *(const uint2*)(featb + (size_t)sw_src(uS) * 32 + li * 4);
            float wS = sw_w(uS);
            acc2[0] = unpack2(U.x) * wS + acc2[0];
            acc2[1] = unpack2(U.y) * wS + acc2[1];
        }
    }

#pragma unroll
    for (int r = 0; r < 2; ++r) {
        acc2[r].x += __shfl_xor(acc2[r].x, 8);
        acc2[r].y += __shfl_xor(acc2[r].y, 8);
        acc2[r].x += __shfl_xor(acc2[r].x, 16);
        acc2[r].y += __shfl_xor(acc2[r].y, 16);
        acc2[r].x += __shfl_xor(acc2[r].x, 32);
        acc2[r].y += __shfl_xor(acc2[r].y, 32);
    }
#pragma unroll
    for (int off = 1; off < 64; off <<= 1) dacc += __shfl_xor(dacc, off);

    if (lane < 8) {
        float inv = (row1 > row0) ? 1.f / dacc : 0.f;
        float4 b0 = ((const float4*)bias)[lane];
        float4 q;
        q.x = acc2[0].x * inv + b0.x;
        q.y = acc2[0].y * inv + b0.y;
        q.z = acc2[1].x * inv + b0.z;
        q.w = acc2[1].y * inv + b0.w;
        ((float4*)(out + (size_t)node * 32))[lane] = q;
    }
}

// ---------------- host ----------------

extern "C" void kernel_launch(void* const* d_in, const int* in_sizes, int n_in,
                              void* d_out, int out_size, void* d_ws, size_t ws_size,
                              hipStream_t stream) {
    const float* features = (const float*)d_in[0];
    const int* esrc = (const int*)d_in[1];
    const int* edst = (const int*)d_in[2];
    const float* W1 = (const float*)d_in[3];
    const float* a1s = (const float*)d_in[4];
    const float* a1d = (const float*)d_in[5];
    const float* b1 = (const float*)d_in[6];
    const float* W2 = (const float*)d_in[7];
    const float* a2s = (const float*)d_in[8];
    const float* a2d = (const float*)d_in[9];
    const float* b2 = (const float*)d_in[10];
    const float* W3 = (const float*)d_in[11];
    const float* a3s = (const float*)d_in[12];
    const float* a3d = (const float*)d_in[13];
    const float* b3 = (const float*)d_in[14];

    int N = in_sizes[0] / 128;
    int E = in_sizes[1];
    int nb = (N + SCAN_CH - 1) / SCAN_CH;

    char* base = (char*)d_ws;
    size_t off = 0;
    auto nxt = [&](size_t bytes) {
        void* p = base + off;
        off += (bytes + 255) & ~(size_t)255;
        return p;
    };
    ushort* Xb = (ushort*)nxt((size_t)N * 128 * 2);   // bf16 features (layer-1 input)
    ushort* Yb = (ushort*)nxt((size_t)N * 128 * 2);   // gemm out / agg4 in
    ushort* Bb = (ushort*)nxt((size_t)N * 128 * 2);   // agg4 out / gemm in
    ushort* Y3b = (ushort*)nxt((size_t)N * 32 * 2);   // gemm32 out
    float* el = (float*)nxt((size_t)N * 4 * 4);
    float* er = (float*)nxt((size_t)N * 4 * 4);
    int* deg8 = (int*)nxt((size_t)N * 8 * 4);         // sharded counters -> shard bases
    int* deg = (int*)nxt((size_t)N * 4);
    int* rowptr = (int*)nxt((size_t)(N + 1) * 4);
    int* csrc = (int*)nxt((size_t)E * 4);
    int* rank = (int*)nxt((size_t)E * 4);
    int* bsum = (int*)nxt((size_t)(nb + 1) * 4);
    int* boff = (int*)nxt((size_t)(nb + 1) * 4);
    ushort* wf1 = (ushort*)nxt(16384 * 2);
    ushort* wf2 = (ushort*)nxt(16384 * 2);
    ushort* wf3 = (ushort*)nxt(4096 * 2);

    int gemm_grid = (N + 63) / 64;
    int n8 = N * 16;
    int cvtblocks = (n8 + 255) / 256;

    // CSR build + input conversions
    hipMemsetAsync(deg8, 0, (size_t)N * 8 * 4, stream);
    hist_kernel<<<(E + 255) / 256, 256, 0, stream>>>(edst, deg8, rank, E, N);
    prep_kernel<<<cvtblocks + 18, 256, 0, stream>>>(features, Xb, n8, cvtblocks,
                                                    W1, wf1, W2, wf2, W3, wf3);
    base8_kernel<<<(N + 255) / 256, 256, 0, stream>>>(deg8, deg, N);
    scan_blocksum<<<nb, 256, 0, stream>>>(deg, bsum, N);
    scan_bsum<<<1, 64, 0, stream>>>(bsum, boff, nb);
    scan_write<<<nb, 256, 0, stream>>>(deg, boff, rowptr, N);
    fill_kernel<<<(E + 255) / 256, 256, 0, stream>>>(esrc, edst, rowptr, rank, deg8,
                                                     csrc, E, N);

    // layer 1: 128 -> 4x32, ELU
    gemm_mfma_kernel<128><<<gemm_grid, 256, 0, stream>>>(Xb, wf1, Yb, a1s, a1d, el, er, N);
    agg4_kernel<true><<<(N + 3) / 4, 256, 0, stream>>>(Yb, el, er, rowptr, csrc, b1, Bb, N);

    // layer 2: 128 -> 4x32, ELU
    gemm_mfma_kernel<128><<<gemm_grid, 256, 0, stream>>>(Bb, wf2, Yb, a2s, a2d, el, er, N);
    agg4_kernel<true><<<(N + 3) / 4, 256, 0, stream>>>(Yb, el, er, rowptr, csrc, b2, Bb, N);

    // layer 3: 128 -> 1x32, no ELU, mean over 1 head = identity
    gemm_mfma_kernel<32><<<gemm_grid, 256, 0, stream>>>(Bb, wf3, Y3b, a3s, a3d, el, er, N);
    agg1_kernel<<<(N + 3) / 4, 256, 0, stream>>>(Y3b, el, er, rowptr, csrc, b3,
                                                 (float*)d_out, N);
}

// Round 19
// 217.557 us; speedup vs baseline: 2.8806x; 1.0044x over previous
//
#include <hip/hip_runtime.h>
#include <hip/hip_fp16.h>

#define NEG_SLOPE 0.2f

typedef unsigned int uint;
typedef unsigned short ushort;
typedef __attribute__((ext_vector_type(8))) short bf16x8;
typedef __attribute__((ext_vector_type(4))) float f32x4;
typedef __attribute__((ext_vector_type(2))) float f32x2;

__device__ __forceinline__ uint pack_bf16x2(float a, float b) {
    uint ba = __float_as_uint(a);
    uint bb = __float_as_uint(b);
    uint ra = (ba + 0x7FFFu + ((ba >> 16) & 1u)) >> 16;
    uint rb = (bb + 0x7FFFu + ((bb >> 16) & 1u)) >> 16;
    return ra | (rb << 16);
}

__device__ __forceinline__ ushort bf16_rne(float v) {
    uint b = __float_as_uint(v);
    return (ushort)((b + 0x7FFFu + ((b >> 16) & 1u)) >> 16);
}

__device__ __forceinline__ f32x2 unpack2(uint u) {
    f32x2 r;
    r.x = __uint_as_float(u << 16);
    r.y = __uint_as_float(u & 0xFFFF0000u);
    return r;
}

__device__ __forceinline__ uint pack_sw(int s, float w) {
    return ((uint)s << 16) | (uint)__half_as_ushort(__float2half_rn(w));
}

__device__ __forceinline__ int sw_src(uint u) { return (int)(u >> 16); }
__device__ __forceinline__ float sw_w(uint u) {
    return __half2float(__ushort_as_half((ushort)(u & 0xFFFFu)));
}

// ---------------- CSR build (8-way sharded histogram, CHUNKED shard) ----------------
// Shard c = blockIdx / cpx: if the dispatcher assigns contiguous block chunks
// per XCD, each shard's counter lines live in one XCD's L2 (no cross-XCD
// atomic line ping-pong). fill recomputes the same c per edge.

__global__ void hist_kernel(const int* __restrict__ dst, int* __restrict__ deg8,
                            int* __restrict__ rank, int E, int N, int cpx) {
    int i = blockIdx.x * 256 + threadIdx.x;
    if (i < E) {
        int c = min(7, (int)blockIdx.x / cpx);
        rank[i] = atomicAdd(&deg8[c * N + dst[i]], 1);
    }
}

// per-node prefix over the 8 shards (in place: deg8 -> shard base), total -> deg
__global__ __launch_bounds__(256) void base8_kernel(int* __restrict__ deg8,
                                                    int* __restrict__ deg, int N) {
    int i = blockIdx.x * 256 + threadIdx.x;
    if (i >= N) return;
    int run = 0;
#pragma unroll
    for (int c = 0; c < 8; ++c) {
        int v = deg8[c * N + i];
        deg8[c * N + i] = run;
        run += v;
    }
    deg[i] = run;
}

#define SCAN_CH 2048

__global__ __launch_bounds__(256) void scan_blocksum(const int* __restrict__ deg,
                                                     int* __restrict__ bsum, int N) {
    int blk = blockIdx.x, t = threadIdx.x;
    int base = blk * SCAN_CH;
    int s = 0;
#pragma unroll
    for (int i = 0; i < SCAN_CH / 256; ++i) {
        int idx = base + t + i * 256;
        if (idx < N) s += deg[idx];
    }
#pragma unroll
    for (int off = 1; off < 64; off <<= 1) s += __shfl_xor(s, off);
    __shared__ int wt[4];
    if ((t & 63) == 0) wt[t >> 6] = s;
    __syncthreads();
    if (t == 0) bsum[blk] = wt[0] + wt[1] + wt[2] + wt[3];
}

__global__ void scan_bsum(const int* __restrict__ bsum, int* __restrict__ boff, int nb) {
    int t = threadIdx.x;
    int orig = (t < nb) ? bsum[t] : 0;
    int v = orig;
#pragma unroll
    for (int off = 1; off < 64; off <<= 1) {
        int u = __shfl_up(v, off);
        if (t >= off) v += u;
    }
    if (t < nb) boff[t] = v - orig;
}

__global__ __launch_bounds__(256) void scan_write(const int* __restrict__ deg,
                                                  const int* __restrict__ boff,
                                                  int* __restrict__ rowptr, int N) {
    int blk = blockIdx.x, t = threadIdx.x;
    int base = blk * SCAN_CH + t * 8;
    int v[8];
    int s = 0;
#pragma unroll
    for (int r = 0; r < 8; ++r) {
        int idx = base + r;
        v[r] = (idx < N) ? deg[idx] : 0;
        s += v[r];
    }
    int lane = t & 63, wid = t >> 6;
    int p = s;
#pragma unroll
    for (int off = 1; off < 64; off <<= 1) {
        int u = __shfl_up(p, off);
        if (lane >= off) p += u;
    }
    __shared__ int wtot[4];
    if (lane == 63) wtot[wid] = p;
    __syncthreads();
    int run = boff[blk];
    for (int w = 0; w < wid; ++w) run += wtot[w];
    run += p - s;
#pragma unroll
    for (int r = 0; r < 8; ++r) {
        int idx = base + r;
        if (idx < N) {
            rowptr[idx] = run;
            run += v[r];
            if (idx == N - 1) rowptr[N] = run;
        }
    }
}

// scatter: pos = rowptr[d] + shard_base[c][d] + within-shard rank
__global__ void fill_kernel(const int* __restrict__ src, const int* __restrict__ dst,
                            const int* __restrict__ rowptr, const int* __restrict__ rank,
                            const int* __restrict__ base8,
                            int* __restrict__ csrc, int E, int N, int cpx) {
    int i = blockIdx.x * 256 + threadIdx.x;
    if (i < E) {
        int c = min(7, (int)blockIdx.x / cpx);
        int d = dst[i];
        __builtin_nontemporal_store(src[i],
                                    csrc + rowptr[d] + base8[c * N + d] + rank[i]);
    }
}

// -------- fused prep: fp32->bf16 cvt + 3x W-fragment pack --------
// frag[ct][kt][lane][j] = W[kt*32 + (lane>>4)*8 + j][ct*16 + (lane&15)]

template <int OUTF>
__device__ __forceinline__ void wpack_body(const float* __restrict__ W,
                                           ushort* __restrict__ wfrag, int idx) {
    constexpr int TOT = (OUTF / 16) * 4 * 64;
    if (idx >= TOT) return;
    int lane = idx & 63;
    int kt = (idx >> 6) & 3;
    int ct = idx >> 8;
    int col = ct * 16 + (lane & 15);
    int k0 = kt * 32 + (lane >> 4) * 8;
    uint4 q;
    q.x = pack_bf16x2(W[(k0 + 0) * OUTF + col], W[(k0 + 1) * OUTF + col]);
    q.y = pack_bf16x2(W[(k0 + 2) * OUTF + col], W[(k0 + 3) * OUTF + col]);
    q.z = pack_bf16x2(W[(k0 + 4) * OUTF + col], W[(k0 + 5) * OUTF + col]);
    q.w = pack_bf16x2(W[(k0 + 6) * OUTF + col], W[(k0 + 7) * OUTF + col]);
    ((uint4*)wfrag)[idx] = q;
}

__global__ __launch_bounds__(256) void prep_kernel(const float* __restrict__ X,
                                                   ushort* __restrict__ Xb, int n8,
                                                   int cvtblocks,
                                                   const float* __restrict__ W1,
                                                   ushort* __restrict__ wf1,
                                                   const float* __restrict__ W2,
                                                   ushort* __restrict__ wf2,
                                                   const float* __restrict__ W3,
                                                   ushort* __restrict__ wf3) {
    int b = blockIdx.x;
    int t = threadIdx.x;
    if (b < cvtblocks) {
        int i = b * 256 + t;
        if (i >= n8) return;
        const float4* xp = (const float4*)X + (size_t)i * 2;
        float4 v0 = xp[0], v1 = xp[1];
        uint4 q;
        q.x = pack_bf16x2(v0.x, v0.y);
        q.y = pack_bf16x2(v0.z, v0.w);
        q.z = pack_bf16x2(v1.x, v1.y);
        q.w = pack_bf16x2(v1.z, v1.w);
        ((uint4*)Xb)[i] = q;
    } else if (b < cvtblocks + 8) {
        wpack_body<128>(W1, wf1, (b - cvtblocks) * 256 + t);
    } else if (b < cvtblocks + 16) {
        wpack_body<128>(W2, wf2, (b - cvtblocks - 8) * 256 + t);
    } else {
        wpack_body<32>(W3, wf3, (b - cvtblocks - 16) * 256 + t);
    }
}

// -------- MFMA GEMM: Yb[N,OUTF] (bf16) = Xb[N,128] @ W + fused el/er --------

template <int OUTF>
__global__ __launch_bounds__(256) void gemm_mfma_kernel(const ushort* __restrict__ Xb,
                                                        const ushort* __restrict__ wfrag,
                                                        ushort* __restrict__ Yb,
                                                        const float* __restrict__ as_,
                                                        const float* __restrict__ ad_,
                                                        float* __restrict__ el,
                                                        float* __restrict__ er, int N) {
    constexpr int H = OUTF / 32;
    constexpr int NCT = OUTF / 16;
    int lane = threadIdx.x & 63;
    int wv = threadIdx.x >> 6;
    int r0 = blockIdx.x * 64 + wv * 16;
    if (r0 >= N) return;
    int lrow = lane & 15;
    int lk8 = lane >> 4;

    bf16x8 afrag[4];
    {
        int arow = min(r0 + lrow, N - 1);
        const ushort* xr = Xb + (size_t)arow * 128;
#pragma unroll
        for (int kt = 0; kt < 4; ++kt)
            afrag[kt] = *(const bf16x8*)(xr + kt * 32 + lk8 * 8);
    }

    float pel[H][4];
    float prr[H][4];
#pragma unroll
    for (int h = 0; h < H; ++h)
#pragma unroll
        for (int j = 0; j < 4; ++j) { pel[h][j] = 0.f; prr[h][j] = 0.f; }

    const bf16x8* wf = (const bf16x8*)wfrag;
#pragma unroll
    for (int ct = 0; ct < NCT; ++ct) {
        f32x4 acc = {0.f, 0.f, 0.f, 0.f};
#pragma unroll
        for (int kt = 0; kt < 4; ++kt) {
            bf16x8 b = wf[(ct * 4 + kt) * 64 + lane];
            acc = __builtin_amdgcn_mfma_f32_16x16x32_bf16(afrag[kt], b, acc, 0, 0, 0);
        }
        int col = ct * 16 + lrow;
        int h = (H == 1) ? 0 : (ct >> 1);
        float asc = as_[col], adc = ad_[col];
#pragma unroll
        for (int j = 0; j < 4; ++j) {
            int row = r0 + lk8 * 4 + j;
            float v = acc[j];
            if (row < N) Yb[(size_t)row * OUTF + col] = bf16_rne(v);
            pel[h][j] = fmaf(v, asc, pel[h][j]);
            prr[h][j] = fmaf(v, adc, prr[h][j]);
        }
    }

#pragma unroll
    for (int h = 0; h < H; ++h)
#pragma unroll
        for (int j = 0; j < 4; ++j) {
            float pe = pel[h][j], pr = prr[h][j];
#pragma unroll
            for (int off = 1; off < 16; off <<= 1) {
                pe += __shfl_xor(pe, off);
                pr += __shfl_xor(pr, off);
            }
            if (lrow == 0) {
                int row = r0 + lk8 * 4 + j;
                if (row < N) {
                    el[row * H + h] = pe;
                    er[row * H + h] = pr;
                }
            }
        }
}

// ---------------- aggregation (H=4, bf16 feat -> bf16 out) ----------------
// 1-deep software pipeline: next batch's csrc + el gathers issue before the
// current batch's bpermute/gather/fma block.

template <bool DOELU>
__global__ __launch_bounds__(256) void agg4_kernel(const ushort* __restrict__ featb,
                                                   const float* __restrict__ el,
                                                   const float* __restrict__ er,
                                                   const int* __restrict__ rowptr,
                                                   const int* __restrict__ csrc,
                                                   const float* __restrict__ bias,
                                                   ushort* __restrict__ outb, int N) {
    int lane = threadIdx.x & 63;
    int node = blockIdx.x * 4 + (threadIdx.x >> 6);
    if (node >= N) return;
    int row0 = __builtin_amdgcn_readfirstlane(rowptr[node]);
    int row1 = __builtin_amdgcn_readfirstlane(rowptr[node + 1]);

    int qe = lane >> 2;
    int qh = lane & 3;
    float ern = er[node * 4 + qh];

    int g = lane >> 4;
    int li = lane & 15;
    int h = li >> 2;
    int ib = (g << 4) + (h << 2);

    float dacc = 0.f;
    f32x2 acc2[4];
#pragma unroll
    for (int r = 0; r < 4; ++r) acc2[r] = (f32x2){0.f, 0.f};

    // pipeline prologue: batch 0 loads
    int e0 = row0 + qe;
    bool v = e0 < row1;
    int s = v ? csrc[e0] : 0;
    float elv = v ? el[s * 4 + qh] : 0.f;

    for (int base = row0; base < row1; base += 16) {
        uint u = 0;
        if (v) {
            float tt = elv + ern;
            tt = tt > 0.f ? tt : NEG_SLOPE * tt;
            float w = __expf(tt);
            dacc += w;
            u = pack_sw(s, w);
        }
        // prefetch next batch (loads in flight during gather/fma below)
        int en = base + 16 + qe;
        bool vn = en < row1;
        int sn = vn ? csrc[en] : 0;
        float elvn = vn ? el[sn * 4 + qh] : 0.f;

        uint u0 = (uint)__builtin_amdgcn_ds_bpermute(ib, (int)u);
        uint u1 = (uint)__builtin_amdgcn_ds_bpermute(ib + 64, (int)u);
        uint u2 = (uint)__builtin_amdgcn_ds_bpermute(ib + 128, (int)u);
        uint u3 = (uint)__builtin_amdgcn_ds_bpermute(ib + 192, (int)u);
        uint4 U0 = *(const uint4*)(featb + (size_t)sw_src(u0) * 128 + li * 8);
        uint4 U1 = *(const uint4*)(featb + (size_t)sw_src(u1) * 128 + li * 8);
        uint4 U2 = *(const uint4*)(featb + (size_t)sw_src(u2) * 128 + li * 8);
        uint4 U3 = *(const uint4*)(featb + (size_t)sw_src(u3) * 128 + li * 8);
        float w0 = sw_w(u0), w1 = sw_w(u1), w2 = sw_w(u2), w3 = sw_w(u3);
        acc2[0] = unpack2(U0.x) * w0 + acc2[0];
        acc2[1] = unpack2(U0.y) * w0 + acc2[1];
        acc2[2] = unpack2(U0.z) * w0 + acc2[2];
        acc2[3] = unpack2(U0.w) * w0 + acc2[3];
        acc2[0] = unpack2(U1.x) * w1 + acc2[0];
        acc2[1] = unpack2(U1.y) * w1 + acc2[1];
        acc2[2] = unpack2(U1.z) * w1 + acc2[2];
        acc2[3] = unpack2(U1.w) * w1 + acc2[3];
        acc2[0] = unpack2(U2.x) * w2 + acc2[0];
        acc2[1] = unpack2(U2.y) * w2 + acc2[1];
        acc2[2] = unpack2(U2.z) * w2 + acc2[2];
        acc2[3] = unpack2(U2.w) * w2 + acc2[3];
        acc2[0] = unpack2(U3.x) * w3 + acc2[0];
        acc2[1] = unpack2(U3.y) * w3 + acc2[1];
        acc2[2] = unpack2(U3.z) * w3 + acc2[2];
        acc2[3] = unpack2(U3.w) * w3 + acc2[3];

        v = vn; s = sn; elv = elvn;
    }

#pragma unroll
    for (int r = 0; r < 4; ++r) {
        acc2[r].x += __shfl_xor(acc2[r].x, 16);
        acc2[r].y += __shfl_xor(acc2[r].y, 16);
        acc2[r].x += __shfl_xor(acc2[r].x, 32);
        acc2[r].y += __shfl_xor(acc2[r].y, 32);
    }
#pragma unroll
    for (int off = 4; off < 64; off <<= 1) dacc += __shfl_xor(dacc, off);
    float d = __int_as_float(
        __builtin_amdgcn_ds_bpermute((li >> 2) << 2, __float_as_int(dacc)));

    if (lane < 16) {
        float inv = (row1 > row0) ? 1.f / d : 0.f;
        const float4* bv = (const float4*)bias + li * 2;
        float4 b0 = bv[0], b1 = bv[1];
        float o[8];
        o[0] = acc2[0].x * inv + b0.x;
        o[1] = acc2[0].y * inv + b0.y;
        o[2] = acc2[1].x * inv + b0.z;
        o[3] = acc2[1].y * inv + b0.w;
        o[4] = acc2[2].x * inv + b1.x;
        o[5] = acc2[2].y * inv + b1.y;
        o[6] = acc2[3].x * inv + b1.z;
        o[7] = acc2[3].y * inv + b1.w;
        if (DOELU) {
#pragma unroll
            for (int r = 0; r < 8; ++r) o[r] = o[r] > 0.f ? o[r] : __expf(o[r]) - 1.f;
        }
        uint4 q;
        q.x = pack_bf16x2(o[0], o[1]);
        q.y = pack_bf16x2(o[2], o[3]);
        q.z = pack_bf16x2(o[4], o[5]);
        q.w = pack_bf16x2(o[6], o[7]);
        *(uint4*)(outb + (size_t)node * 128 + li * 8) = q;
    }
}

// ---------------- aggregation (H=1, bf16 feat -> fp32 out) ----------------

__global__ __launch_bounds__(256) void agg1_kernel(const ushort* __restrict__ featb,
                                                   const float* __restrict__ el,
                                                   const float* __restrict__ er,
                                                   const int* __restrict__ rowptr,
                                                   const int* __restrict__ csrc,
                                                   const float* __restrict__ bias,
                                                   float* __restrict__ out, int N) {
    int lane = threadIdx.x & 63;
    int node = blockIdx.x * 4 + (threadIdx.x >> 6);
    if (node >= N) return;
    int row0 = __builtin_amdgcn_readfirstlane(rowptr[node]);
    int row1 = __builtin_amdgcn_readfirstlane(rowptr[node + 1]);

    float ern = er[node];
    int g = lane >> 3;
    int li = lane & 7;

    float dacc = 0.f;
    f32x2 acc2[2];
    acc2[0] = (f32x2){0.f, 0.f};
    acc2[1] = (f32x2){0.f, 0.f};

    for (int base = row0; base < row1; base += 64) {
        int e = base + lane;
        uint u = 0;
        if (e < row1) {
            int s = csrc[e];
            float t0 = el[s] + ern;
            t0 = t0 > 0.f ? t0 : NEG_SLOPE * t0;
            float w0 = __expf(t0);
            dacc += w0;
            u = pack_sw(s, w0);
        }
        int cnt = min(row1 - base, 64);
        int iters = (cnt + 7) >> 3;
        int it = 0;
        for (; it + 1 < iters; it += 2) {
            int idxA = ((it << 3) + g) << 2;
            int idxB = (((it + 1) << 3) + g) << 2;
            uint uA = (uint)__builtin_amdgcn_ds_bpermute(idxA, (int)u);
            uint uB = (uint)__builtin_amdgcn_ds_bpermute(idxB, (int)u);
            uint2 UA = *(const uint2*)(featb + (size_t)sw_src(uA) * 32 + li * 4);
            uint2 UB = *(const uint2*)(featb + (size_t)sw_src(uB) * 32 + li * 4);
            float wA = sw_w(uA), wB = sw_w(uB);
            acc2[0] = unpack2(UA.x) * wA + acc2[0];
            acc2[1] = unpack2(UA.y) * wA + acc2[1];
            acc2[0] = unpack2(UB.x) * wB + acc2[0];
            acc2[1] = unpack2(UB.y) * wB + acc2[1];
        }
        if (it < iters) {
            int idx = ((it << 3) + g) << 2;
            uint uS = (uint)__builtin_amdgcn_ds_bpermute(idx, (int)u);
            uint2 U = *(const uint2*)(featb + (size_t)sw_src(uS) * 32 + li * 4);
            float wS = sw_w(uS);
            acc2[0] = unpack2(U.x) * wS + acc2[0];
            acc2[1] = unpack2(U.y) * wS + acc2[1];
        }
    }

#pragma unroll
    for (int r = 0; r < 2; ++r) {
        acc2[r].x += __shfl_xor(acc2[r].x, 8);
        acc2[r].y += __shfl_xor(acc2[r].y, 8);
        acc2[r].x += __shfl_xor(acc2[r].x, 16);
        acc2[r].y += __shfl_xor(acc2[r].y, 16);
        acc2[r].x += __shfl_xor(acc2[r].x, 32);
        acc2[r].y += __shfl_xor(acc2[r].y, 32);
    }
#pragma unroll
    for (int off = 1; off < 64; off <<= 1) dacc += __shfl_xor(dacc, off);

    if (lane < 8) {
        float inv = (row1 > row0) ? 1.f / dacc : 0.f;
        float4 b0 = ((const float4*)bias)[lane];
        float4 q;
        q.x = acc2[0].x * inv + b0.x;
        q.y = acc2[0].y * inv + b0.y;
        q.z = acc2[1].x * inv + b0.z;
        q.w = acc2[1].y * inv + b0.w;
        ((float4*)(out + (size_t)node * 32))[lane] = q;
    }
}

// ---------------- host ----------------

extern "C" void kernel_launch(void* const* d_in, const int* in_sizes, int n_in,
                              void* d_out, int out_size, void* d_ws, size_t ws_size,
                              hipStream_t stream) {
    const float* features = (const float*)d_in[0];
    const int* esrc = (const int*)d_in[1];
    const int* edst = (const int*)d_in[2];
    const float* W1 = (const float*)d_in[3];
    const float* a1s = (const float*)d_in[4];
    const float* a1d = (const float*)d_in[5];
    const float* b1 = (const float*)d_in[6];
    const float* W2 = (const float*)d_in[7];
    const float* a2s = (const float*)d_in[8];
    const float* a2d = (const float*)d_in[9];
    const float* b2 = (const float*)d_in[10];
    const float* W3 = (const float*)d_in[11];
    const float* a3s = (const float*)d_in[12];
    const float* a3d = (const float*)d_in[13];
    const float* b3 = (const float*)d_in[14];

    int N = in_sizes[0] / 128;
    int E = in_sizes[1];
    int nb = (N + SCAN_CH - 1) / SCAN_CH;

    char* base = (char*)d_ws;
    size_t off = 0;
    auto nxt = [&](size_t bytes) {
        void* p = base + off;
        off += (bytes + 255) & ~(size_t)255;
        return p;
    };
    ushort* Xb = (ushort*)nxt((size_t)N * 128 * 2);   // bf16 features (layer-1 input)
    ushort* Yb = (ushort*)nxt((size_t)N * 128 * 2);   // gemm out / agg4 in
    ushort* Bb = (ushort*)nxt((size_t)N * 128 * 2);   // agg4 out / gemm in
    ushort* Y3b = (ushort*)nxt((size_t)N * 32 * 2);   // gemm32 out
    float* el = (float*)nxt((size_t)N * 4 * 4);
    float* er = (float*)nxt((size_t)N * 4 * 4);
    int* deg8 = (int*)nxt((size_t)N * 8 * 4);         // sharded counters -> shard bases
    int* deg = (int*)nxt((size_t)N * 4);
    int* rowptr = (int*)nxt((size_t)(N + 1) * 4);
    int* csrc = (int*)nxt((size_t)E * 4);
    int* rank = (int*)nxt((size_t)E * 4);
    int* bsum = (int*)nxt((size_t)(nb + 1) * 4);
    int* boff = (int*)nxt((size_t)(nb + 1) * 4);
    ushort* wf1 = (ushort*)nxt(16384 * 2);
    ushort* wf2 = (ushort*)nxt(16384 * 2);
    ushort* wf3 = (ushort*)nxt(4096 * 2);

    int gemm_grid = (N + 63) / 64;
    int n8 = N * 16;
    int cvtblocks = (n8 + 255) / 256;
    int eblocks = (E + 255) / 256;
    int cpx = (eblocks + 7) / 8;   // blocks per shard (chunked XCD assumption)

    // CSR build + input conversions
    hipMemsetAsync(deg8, 0, (size_t)N * 8 * 4, stream);
    hist_kernel<<<eblocks, 256, 0, stream>>>(edst, deg8, rank, E, N, cpx);
    prep_kernel<<<cvtblocks + 18, 256, 0, stream>>>(features, Xb, n8, cvtblocks,
                                                    W1, wf1, W2, wf2, W3, wf3);
    base8_kernel<<<(N + 255) / 256, 256, 0, stream>>>(deg8, deg, N);
    scan_blocksum<<<nb, 256, 0, stream>>>(deg, bsum, N);
    scan_bsum<<<1, 64, 0, stream>>>(bsum, boff, nb);
    scan_write<<<nb, 256, 0, stream>>>(deg, boff, rowptr, N);
    fill_kernel<<<eblocks, 256, 0, stream>>>(esrc, edst, rowptr, rank, deg8,
                                             csrc, E, N, cpx);

    // layer 1: 128 -> 4x32, ELU
    gemm_mfma_kernel<128><<<gemm_grid, 256, 0, stream>>>(Xb, wf1, Yb, a1s, a1d, el, er, N);
    agg4_kernel<true><<<(N + 3) / 4, 256, 0, stream>>>(Yb, el, er, rowptr, csrc, b1, Bb, N);

    // layer 2: 128 -> 4x32, ELU
    gemm_mfma_kernel<128><<<gemm_grid, 256, 0, stream>>>(Bb, wf2, Yb, a2s, a2d, el, er, N);
    agg4_kernel<true><<<(N + 3) / 4, 256, 0, stream>>>(Yb, el, er, rowptr, csrc, b2, Bb, N);

    // layer 3: 128 -> 1x32, no ELU, mean over 1 head = identity
    gemm_mfma_kernel<32><<<gemm_grid, 256, 0, stream>>>(Bb, wf3, Y3b, a3s, a3d, el, er, N);
    agg1_kernel<<<(N + 3) / 4, 256, 0, stream>>>(Y3b, el, er, rowptr, csrc, b3,
                                                 (float*)d_out, N);
}